// Round 9
// baseline (310.766 us; speedup 1.0000x reference)
//
#include <hip/hip_runtime.h>
#include <hip/hip_bf16.h>

using bf16 = __hip_bfloat16;
typedef __attribute__((ext_vector_type(4))) float floatx4;
typedef __attribute__((ext_vector_type(8))) __bf16 bf16x8;
typedef __attribute__((ext_vector_type(4))) __bf16 bf16x4;

#define LGKM_WAIT() asm volatile("s_waitcnt lgkmcnt(0)" ::: "memory")

// XCD-aware remap (XCD = linear_block_id % 8 heuristic): each XCD owns a
// b-pair so activation slices stay L2-resident. 1024 = 16bn x 4bo x 16b.
__device__ __forceinline__ void remap1024(int L, int& bn, int& bo, int& b)
{
    const int xcd = L & 7, slot = L >> 3;       // slot 0..127
    b  = (xcd << 1) | (slot & 1);
    bo = (slot >> 1) & 3;
    bn = slot >> 3;                              // 0..15
}

// ---------------------------------------------------------------------------
// Weight prep: fp32 [O=256][K=256][taps] -> bf16 frag-ordered
// [t][kc][o 0..255][kk 0..31]
// ---------------------------------------------------------------------------
__device__ __forceinline__ void prep_one(const float* __restrict__ src,
                                         bf16* __restrict__ dst, int idx, int ntaps)
{
    const int kk = idx & 31, o = (idx >> 5) & 255, kc = (idx >> 13) & 7, t = idx >> 16;
    dst[idx] = __float2bfloat16(src[(o * 256 + kc * 32 + kk) * ntaps + t]);
}

__global__ __launch_bounds__(256) void prep_all(
    const float* __restrict__ x,
    const float* __restrict__ w1, const float* __restrict__ w2,
    const float* __restrict__ qw, const float* __restrict__ kw,
    const float* __restrict__ vw, const float* __restrict__ ow,
    bf16* __restrict__ xk, bf16* __restrict__ w1f, bf16* __restrict__ w2f,
    bf16* __restrict__ qwf, bf16* __restrict__ kwf,
    bf16* __restrict__ vwf, bf16* __restrict__ owf)
{
    __shared__ float T[64][65];
    const int blk = blockIdx.x, tid = threadIdx.x;
    if (blk < 1024) {
        const int n0 = (blk & 15) * 64, c0 = ((blk >> 4) & 3) * 64, b = blk >> 6;
        #pragma unroll
        for (int it = 0; it < 4; ++it) {
            const int tau = tid + it * 256;
            const int c = tau >> 4, seg = tau & 15;
            const float4 vv = *(const float4*)&x[((b * 256 + c0 + c) << 10) + n0 + seg * 4];
            T[seg * 4 + 0][c] = vv.x; T[seg * 4 + 1][c] = vv.y;
            T[seg * 4 + 2][c] = vv.z; T[seg * 4 + 3][c] = vv.w;
        }
        __syncthreads();
        #pragma unroll
        for (int it = 0; it < 2; ++it) {
            const int tau = tid + it * 256;
            const int n = tau >> 3, seg = tau & 7;
            bf16x8 o8;
            #pragma unroll
            for (int q = 0; q < 8; ++q) o8[q] = (__bf16)T[n][seg * 8 + q];
            const int c = c0 + seg * 8;
            *(bf16x8*)&xk[((((b << 3) + (c >> 5)) << 10) + n0 + n) * 32 + (c & 31)] = o8;
        }
    } else if (blk < 2176) {
        const int base = (blk - 1024) * 256 + tid;
        #pragma unroll
        for (int k = 0; k < 4; ++k) {
            const int idx = base + k * 294912;
            if (idx < 589824) prep_one(w1, w1f, idx, 9);
            else              prep_one(w2, w2f, idx - 589824, 9);
        }
    } else {
        const int r = (blk - 2176) * 256 + tid;
        prep_one(qw, qwf, r, 1);
        prep_one(kw, kwf, r, 1);
        prep_one(vw, vwf, r, 1);
        prep_one(ow, owf, r, 1);
    }
}

// ---------------------------------------------------------------------------
// Conv3x3 GEMM: 64sp x 64oc tile, 1024 blocks (4/CU), XCD-swizzled.
// Double-buffered LDS halo (4y x 34x x 32k, pad 40), 1 barrier/kc, act
// prefetch + depth-1 weight ping-pong. Waves 2x2 -> 32sp x 32oc, acc[2][2].
// MODE 0: BN+ReLU -> bf16 k-blocked | MODE 1: BN -> fp32 c-major (repacked)
// ---------------------------------------------------------------------------
template<int MODE>
__global__ __launch_bounds__(256) void conv_k(
    const bf16* __restrict__ Wf, const bf16* __restrict__ Act,
    const float* __restrict__ bias,
    const float* __restrict__ gam, const float* __restrict__ bet,
    const float* __restrict__ mu, const float* __restrict__ var,
    void* __restrict__ outp)
{
    __shared__ __align__(16) unsigned char smb[21760];  // 2 x 10880 staging

    int bn, bo, b; remap1024(blockIdx.x, bn, bo, b);
    const int tid = threadIdx.x;
    const int wave = tid >> 6, lane = tid & 63;
    const int quad = lane >> 4, l16 = lane & 15;
    const int wm = wave & 1, wn = wave >> 1;

    // staging: 136 halo rows (4y x 34x) x 4 chunks = 544 slots
    int srow[3], scol[3], sn[3]; bool sval[3];
    #pragma unroll
    for (int it = 0; it < 3; ++it) {
        const int s = tid + it * 256;
        const int row = s >> 2;
        const int yi = row / 34, x34 = row - yi * 34;
        const int gy = bn * 2 - 1 + yi, gx = x34 - 1;
        sval[it] = (s < 544) & (gy >= 0) & (gy < 32) & (gx >= 0) & (gx < 32);
        sn[it] = (gy << 5) + gx;
        srow[it] = row; scol[it] = (s & 3) * 8;
    }

    const bf16* __restrict__ act0 = Act + ((size_t)b << 18);
    bf16x8 rg[3];
    #pragma unroll
    for (int it = 0; it < 3; ++it) {
        bf16x8 v = {};
        if (sval[it]) v = *(const bf16x8*)&act0[sn[it] * 32 + scol[it]];
        rg[it] = v;
    }
    {
        bf16* st = (bf16*)smb;
        #pragma unroll
        for (int it = 0; it < 3; ++it)
            if (tid + it * 256 < 544) *(bf16x8*)&st[srow[it] * 40 + scol[it]] = rg[it];
    }
    __syncthreads();

    floatx4 acc[2][2] = {};

    bf16x8 wcur[2];
    #pragma unroll
    for (int p = 0; p < 2; ++p)  // (kc=0, t=0)
        wcur[p] = *(const bf16x8*)&Wf[(((0 * 8 + 0) << 8) + bo * 64 + wn * 32 + p * 16 + l16) * 32 + quad * 8];

    for (int kc = 0; kc < 8; ++kc) {
        if (kc < 7) {
            const bf16* __restrict__ actn = act0 + ((kc + 1) << 15);
            #pragma unroll
            for (int it = 0; it < 3; ++it) {
                bf16x8 v = {};
                if (sval[it]) v = *(const bf16x8*)&actn[sn[it] * 32 + scol[it]];
                rg[it] = v;
            }
        }
        const bf16* __restrict__ cur = (const bf16*)(smb + (kc & 1) * 10880);
        #pragma unroll
        for (int t = 0; t < 9; ++t) {
            // issue next-tap weight loads first (depth-1 pipeline)
            const int nt  = (t == 8) ? 0 : t + 1;
            const int nkc = (t == 8) ? kc + 1 : kc;
            bf16x8 wnxt[2] = {};
            if (nkc < 8) {
                #pragma unroll
                for (int p = 0; p < 2; ++p)
                    wnxt[p] = *(const bf16x8*)&Wf[(((nt * 8 + nkc) << 8) + bo * 64 + wn * 32 + p * 16 + l16) * 32 + quad * 8];
            }
            const int dy = t / 3 - 1, dx = t % 3 - 1;
            bf16x8 af[2];
            #pragma unroll
            for (int p = 0; p < 2; ++p) {
                const int m = wm * 32 + p * 16 + l16;   // local spatial 0..63
                const int row = ((m >> 5) + 1 + dy) * 34 + ((m & 31) + 1 + dx);
                af[p] = *(const bf16x8*)&cur[row * 40 + quad * 8];
            }
            #pragma unroll
            for (int i = 0; i < 2; ++i)
                #pragma unroll
                for (int j = 0; j < 2; ++j)
                    acc[i][j] = __builtin_amdgcn_mfma_f32_16x16x32_bf16(af[i], wcur[j], acc[i][j], 0, 0, 0);
            wcur[0] = wnxt[0]; wcur[1] = wnxt[1];
        }
        if (kc < 7) {
            bf16* nxt = (bf16*)(smb + ((kc + 1) & 1) * 10880);
            #pragma unroll
            for (int it = 0; it < 3; ++it)
                if (tid + it * 256 < 544) *(bf16x8*)&nxt[srow[it] * 40 + scol[it]] = rg[it];
        }
        __syncthreads();
    }

    if constexpr (MODE == 0) {
        // bf16 k-blocked out [b][oc>>5][n][oc&31]; per-wave repack [n 32][40]
        bf16* rp = (bf16*)(smb + wave * 2560);
        #pragma unroll
        for (int i = 0; i < 2; ++i)
            #pragma unroll
            for (int j = 0; j < 2; ++j) {
                const int oc = bo * 64 + wn * 32 + j * 16 + l16;
                const float inv = gam[oc] * rsqrtf(var[oc] + 1e-5f);
                const float sh = bet[oc] - mu[oc] * inv;
                const float bs = bias[oc];
                #pragma unroll
                for (int r = 0; r < 4; ++r) {
                    const float v = (acc[i][j][r] + bs) * inv + sh;
                    rp[(i * 16 + quad * 4 + r) * 40 + j * 16 + l16] =
                        __float2bfloat16(v < 0.0f ? 0.0f : v);
                }
            }
        LGKM_WAIT();
        const int kc2 = bo * 2 + wn;
        bf16* dst = (bf16*)outp + ((((size_t)b << 3) + kc2) << 15) + (bn * 64 + wm * 32) * 32;
        #pragma unroll
        for (int it = 0; it < 2; ++it) {
            const int s = it * 64 + lane;
            const int nl = s >> 2, cp = (s & 3) * 8;
            *(bf16x8*)&dst[nl * 32 + cp] = *(const bf16x8*)&rp[nl * 40 + cp];
        }
    } else {
        // fp32 c-major out; per-wave repack [oc 32][36]
        float* rp = (float*)(smb + wave * 4608);
        #pragma unroll
        for (int i = 0; i < 2; ++i)
            #pragma unroll
            for (int j = 0; j < 2; ++j) {
                const int oc = bo * 64 + wn * 32 + j * 16 + l16;
                const float inv = gam[oc] * rsqrtf(var[oc] + 1e-5f);
                const float sh = bet[oc] - mu[oc] * inv;
                const float bs = bias[oc];
                float4 o;
                o.x = (acc[i][j][0] + bs) * inv + sh;
                o.y = (acc[i][j][1] + bs) * inv + sh;
                o.z = (acc[i][j][2] + bs) * inv + sh;
                o.w = (acc[i][j][3] + bs) * inv + sh;
                *(float4*)&rp[(j * 16 + l16) * 36 + i * 16 + quad * 4] = o;
            }
        LGKM_WAIT();
        const int n0 = bn * 64 + wm * 32;
        #pragma unroll
        for (int it = 0; it < 4; ++it) {
            const int s = it * 64 + lane;
            const int ocl = s >> 3, nch = s & 7;
            const int oc = bo * 64 + wn * 32 + ocl;
            float4 v = *(const float4*)&rp[ocl * 36 + nch * 4];
            *(float4*)&((float*)outp)[((b * 256 + oc) << 10) + n0 + nch * 4] = v;
        }
    }
}

// ---------------------------------------------------------------------------
// Fused q/k/v projections (128sp x 64oc, barrier-free mainloop), XCD-swizzled.
// q pre-scaled by log2(e)/sqrt(32) for the exp2 softmax path.
// ---------------------------------------------------------------------------
__global__ __launch_bounds__(256) void qkv_k(
    const bf16* __restrict__ Wq, const bf16* __restrict__ Wk, const bf16* __restrict__ Wv,
    const bf16* __restrict__ Act,
    const float* __restrict__ bq, const float* __restrict__ bk, const float* __restrict__ bv,
    bf16* __restrict__ Oq, bf16* __restrict__ Ok, bf16* __restrict__ Ov, float qscale)
{
    __shared__ __align__(16) unsigned char qsm[20480];
    const int L = blockIdx.x;
    const int xcd = L & 7, slot = L >> 3;        // 0..191
    const int b = (xcd << 1) | (slot & 1);
    const int s1 = slot >> 1;                    // 0..95
    const int by = s1 % 12, bn = s1 / 12;        // by 0..11, bn 0..7
    const int sel = by >> 2, bo = by & 3;
    const bf16* __restrict__ Wf = (sel == 0) ? Wq : (sel == 1) ? Wk : Wv;
    const float* __restrict__ bias = (sel == 0) ? bq : (sel == 1) ? bk : bv;
    const float scale = (sel == 0) ? qscale : 1.0f;

    const int tid = threadIdx.x;
    const int wave = tid >> 6, lane = tid & 63;
    const int quad = lane >> 4, l16 = lane & 15;
    const int wm = wave & 1, wn = wave >> 1;

    floatx4 acc[4][2] = {};

    for (int kc = 0; kc < 8; ++kc) {
        const bf16* __restrict__ actk = Act + ((size_t)b << 18) + (kc << 15);
        bf16x8 af[4], wf[2];
        #pragma unroll
        for (int p = 0; p < 4; ++p)
            af[p] = *(const bf16x8*)&actk[(bn * 128 + wm * 64 + p * 16 + l16) * 32 + quad * 8];
        #pragma unroll
        for (int p = 0; p < 2; ++p)
            wf[p] = *(const bf16x8*)&Wf[(((kc << 8) + bo * 64 + wn * 32 + p * 16 + l16) << 5) + quad * 8];
        #pragma unroll
        for (int i = 0; i < 4; ++i)
            #pragma unroll
            for (int j = 0; j < 2; ++j)
                acc[i][j] = __builtin_amdgcn_mfma_f32_16x16x32_bf16(af[i], wf[j], acc[i][j], 0, 0, 0);
    }

    if (sel < 2) {
        bf16* rp = (bf16*)(qsm + wave * 5120);   // [n_local 64][40]
        #pragma unroll
        for (int i = 0; i < 4; ++i)
            #pragma unroll
            for (int j = 0; j < 2; ++j) {
                const int oc = bo * 64 + wn * 32 + j * 16 + l16;
                const float bs = bias[oc];
                #pragma unroll
                for (int r = 0; r < 4; ++r)
                    rp[(i * 16 + quad * 4 + r) * 40 + j * 16 + l16] =
                        __float2bfloat16((acc[i][j][r] + bs) * scale);
            }
        LGKM_WAIT();
        bf16* __restrict__ outp = (sel == 0) ? Oq : Ok;
        const int h = bo * 2 + wn;
        bf16* dst = outp + ((((size_t)b << 3) + h) << 15) + (bn * 128 + wm * 64) * 32;
        #pragma unroll
        for (int it = 0; it < 4; ++it) {
            const int s = it * 64 + lane;
            const int nl = s >> 2, cp = (s & 3) * 8;
            *(bf16x8*)&dst[nl * 32 + cp] = *(const bf16x8*)&rp[nl * 40 + cp];
        }
    } else {
        bf16* rp = (bf16*)(qsm + wave * 4608);   // [oc 32][72]
        #pragma unroll
        for (int i = 0; i < 4; ++i)
            #pragma unroll
            for (int j = 0; j < 2; ++j) {
                const int oc = bo * 64 + wn * 32 + j * 16 + l16;
                const float bs = bias[oc];
                bf16x4 o4;
                #pragma unroll
                for (int r = 0; r < 4; ++r) o4[r] = (__bf16)(acc[i][j][r] + bs);
                *(bf16x4*)&rp[(j * 16 + l16) * 72 + i * 16 + quad * 4] = o4;
            }
        LGKM_WAIT();
        const int n0 = bn * 128 + wm * 64;
        #pragma unroll
        for (int it = 0; it < 4; ++it) {
            const int s = it * 64 + lane;
            const int ocl = s >> 3, nch = s & 7;
            const int oc = bo * 64 + wn * 32 + ocl;
            *(bf16x8*)&Ov[((b * 256 + oc) << 10) + n0 + nch * 8] =
                *(const bf16x8*)&rp[ocl * 72 + nch * 8];
        }
    }
}

// ---------------------------------------------------------------------------
// Flash attention: S^T = K Q^T, exp2-domain softmax (Q pre-scaled by log2e/√d).
// XCD swizzle: h = L%8 -> each XCD owns one head (K/V 2 MB, L2-resident).
// 16 queries/wave, 2048 blocks (8/CU). Per-wave P in LDS, no barriers.
// ---------------------------------------------------------------------------
__global__ __launch_bounds__(256) void attn_kernel(
    const bf16* __restrict__ Q, const bf16* __restrict__ K,
    const bf16* __restrict__ V, bf16* __restrict__ O)
{
    __shared__ __align__(16) bf16 Pl[4][16][136];  // 17408 B

    const int L = blockIdx.x;
    const int h = L & 7, slot = L >> 3;
    const int b = slot & 15, qb = slot >> 4;       // qb 0..15
    const int tid = threadIdx.x;
    const int wave = tid >> 6, lane = tid & 63;
    const int quad = lane >> 4, l16 = lane & 15;

    const bf16* __restrict__ Qh = Q + ((((size_t)b << 3) + h) << 15);
    const bf16* __restrict__ Kh = K + ((((size_t)b << 3) + h) << 15);
    const int qrow0 = qb * 64 + wave * 16;

    bf16x8 qf = *(const bf16x8*)&Qh[(qrow0 + l16) * 32 + quad * 8];

    float lp = 0.0f;
    floatx4 oacc[2] = {};

    for (int kt = 0; kt < 8; ++kt) {
        bf16x8 kf[8];
        #pragma unroll
        for (int kb = 0; kb < 8; ++kb)
            kf[kb] = *(const bf16x8*)&Kh[(kt * 128 + kb * 16 + l16) * 32 + quad * 8];
        bf16x8 vb[2][4];
        #pragma unroll
        for (int jd = 0; jd < 2; ++jd)
            #pragma unroll
            for (int kk = 0; kk < 4; ++kk)
                vb[jd][kk] = *(const bf16x8*)&V[((b * 256 + h * 32 + jd * 16 + l16) << 10)
                                               + kt * 128 + kk * 32 + quad * 8];

        // S^T tile: D[row=key=kb*16+quad*4+r][col=q=l16]; p = 2^s
        #pragma unroll
        for (int kb = 0; kb < 8; ++kb) {
            floatx4 zz = {0.f, 0.f, 0.f, 0.f};
            floatx4 st = __builtin_amdgcn_mfma_f32_16x16x32_bf16(kf[kb], qf, zz, 0, 0, 0);
            const float e0 = __builtin_amdgcn_exp2f(st[0]);
            const float e1 = __builtin_amdgcn_exp2f(st[1]);
            const float e2 = __builtin_amdgcn_exp2f(st[2]);
            const float e3 = __builtin_amdgcn_exp2f(st[3]);
            lp += (e0 + e1) + (e2 + e3);
            bf16x4 p4 = {(__bf16)e0, (__bf16)e1, (__bf16)e2, (__bf16)e3};
            *(bf16x4*)&Pl[wave][l16][kb * 16 + quad * 4] = p4;
        }

        // O += V P : A[m=d][k=key], B[k=key][n=q]
        #pragma unroll
        for (int kk = 0; kk < 4; ++kk) {
            bf16x8 pf = *(const bf16x8*)&Pl[wave][l16][kk * 32 + quad * 8];
            #pragma unroll
            for (int jd = 0; jd < 2; ++jd)
                oacc[jd] = __builtin_amdgcn_mfma_f32_16x16x32_bf16(vb[jd][kk], pf, oacc[jd], 0, 0, 0);
        }
    }

    float l = lp;
    l += __shfl_xor(l, 16, 64);
    l += __shfl_xor(l, 32, 64);
    const float inv = 1.0f / l;
    bf16* __restrict__ Oh = O + ((((size_t)b << 3) + h) << 15);
    const int qn = qrow0 + l16;
    #pragma unroll
    for (int jd = 0; jd < 2; ++jd) {
        bf16x4 o4;
        #pragma unroll
        for (int r = 0; r < 4; ++r) o4[r] = (__bf16)(oacc[jd][r] * inv);
        *(bf16x4*)&Oh[qn * 32 + jd * 16 + quad * 4] = o4;
    }
}

// ---------------------------------------------------------------------------
// Final: out = relu(c2 + sigmoid(gate)*(ow@attn + ob) + x), fp32 c-major.
// 64sp x 64oc, 1024 blocks (4/CU), XCD-swizzled; per-wave repack epilogue.
// ---------------------------------------------------------------------------
__global__ __launch_bounds__(256) void fi_k(
    const bf16* __restrict__ Wf, const bf16* __restrict__ Act,
    const float* __restrict__ bias,
    const float* __restrict__ c2, const float* __restrict__ resid,
    const float* __restrict__ gate, float* __restrict__ outp)
{
    __shared__ __align__(16) unsigned char fsm[18432];
    int bn, bo, b; remap1024(blockIdx.x, bn, bo, b);
    const int tid = threadIdx.x;
    const int wave = tid >> 6, lane = tid & 63;
    const int quad = lane >> 4, l16 = lane & 15;
    const int wm = wave & 1, wn = wave >> 1;

    floatx4 acc[2][2] = {};

    for (int kc = 0; kc < 8; ++kc) {
        const bf16* __restrict__ actk = Act + ((size_t)b << 18) + (kc << 15);
        bf16x8 af[2], wf[2];
        #pragma unroll
        for (int p = 0; p < 2; ++p)
            af[p] = *(const bf16x8*)&actk[(bn * 64 + wm * 32 + p * 16 + l16) * 32 + quad * 8];
        #pragma unroll
        for (int p = 0; p < 2; ++p)
            wf[p] = *(const bf16x8*)&Wf[(((kc << 8) + bo * 64 + wn * 32 + p * 16 + l16) << 5) + quad * 8];
        #pragma unroll
        for (int i = 0; i < 2; ++i)
            #pragma unroll
            for (int j = 0; j < 2; ++j)
                acc[i][j] = __builtin_amdgcn_mfma_f32_16x16x32_bf16(af[i], wf[j], acc[i][j], 0, 0, 0);
    }

    const float sg = 1.0f / (1.0f + __expf(-gate[0]));

    float* rp = (float*)(fsm + wave * 4608);   // [oc 32][36]
    #pragma unroll
    for (int i = 0; i < 2; ++i)
        #pragma unroll
        for (int j = 0; j < 2; ++j) {
            const int oc = bo * 64 + wn * 32 + j * 16 + l16;
            const float bs = bias[oc];
            float4 o;
            o.x = acc[i][j][0] + bs; o.y = acc[i][j][1] + bs;
            o.z = acc[i][j][2] + bs; o.w = acc[i][j][3] + bs;
            *(float4*)&rp[(j * 16 + l16) * 36 + i * 16 + quad * 4] = o;
        }
    LGKM_WAIT();
    const int n0 = bn * 64 + wm * 32;
    #pragma unroll
    for (int it = 0; it < 4; ++it) {
        const int s = it * 64 + lane;
        const int ocl = s >> 3, nch = s & 7;
        const int oc = bo * 64 + wn * 32 + ocl;
        const int idx = ((b * 256 + oc) << 10) + n0 + nch * 4;
        float4 v = *(const float4*)&rp[ocl * 36 + nch * 4];
        const float4 cc = *(const float4*)&c2[idx];
        const float4 rr = *(const float4*)&resid[idx];
        float4 o;
        o.x = cc.x + sg * v.x + rr.x; o.y = cc.y + sg * v.y + rr.y;
        o.z = cc.z + sg * v.z + rr.z; o.w = cc.w + sg * v.w + rr.w;
        o.x = o.x < 0.0f ? 0.0f : o.x; o.y = o.y < 0.0f ? 0.0f : o.y;
        o.z = o.z < 0.0f ? 0.0f : o.z; o.w = o.w < 0.0f ? 0.0f : o.w;
        *(float4*)&outp[idx] = o;
    }
}

extern "C" void kernel_launch(void* const* d_in, const int* in_sizes, int n_in,
                              void* d_out, int out_size, void* d_ws, size_t ws_size,
                              hipStream_t stream)
{
    const float* x    = (const float*)d_in[0];
    const float* w1   = (const float*)d_in[1];
    const float* cb1  = (const float*)d_in[2];
    const float* g1   = (const float*)d_in[3];
    const float* be1  = (const float*)d_in[4];
    const float* mu1  = (const float*)d_in[5];
    const float* va1  = (const float*)d_in[6];
    const float* w2   = (const float*)d_in[7];
    const float* cb2  = (const float*)d_in[8];
    const float* g2   = (const float*)d_in[9];
    const float* be2  = (const float*)d_in[10];
    const float* mu2  = (const float*)d_in[11];
    const float* va2  = (const float*)d_in[12];
    const float* qw   = (const float*)d_in[13];
    const float* qb_  = (const float*)d_in[14];
    const float* kw   = (const float*)d_in[15];
    const float* kb_  = (const float*)d_in[16];
    const float* vw   = (const float*)d_in[17];
    const float* vb_  = (const float*)d_in[18];
    const float* ow   = (const float*)d_in[19];
    const float* ob_  = (const float*)d_in[20];
    const float* gate = (const float*)d_in[21];

    char* ws = (char*)d_ws;
    bf16*  xk    = (bf16*) (ws + 0);          //  8,388,608  k-blocked x
    bf16*  y1k   = (bf16*) (ws + 8388608);    //  8,388,608  conv1 out k-blocked
    bf16*  attnk = (bf16*) (ws + 8388608);    //  reuse (y1k dead after conv2)
    float* c2    = (float*)(ws + 16777216);   // 16,777,216  conv2 out c-major fp32
    bf16*  qT    = (bf16*) (ws + 33554432);   //  8,388,608  head-blocked
    bf16*  kT    = (bf16*) (ws + 41943040);   //  8,388,608  head-blocked
    bf16*  vbuf  = (bf16*) (ws + 50331648);   //  8,388,608  c-major
    bf16*  w1f   = (bf16*) (ws + 58720256);
    bf16*  w2f   = (bf16*) (ws + 59899904);
    bf16*  qwf   = (bf16*) (ws + 61079552);
    bf16*  kwf   = (bf16*) (ws + 61210624);
    bf16*  vwf   = (bf16*) (ws + 61341696);
    bf16*  owf   = (bf16*) (ws + 61472768);

    dim3 blk(256, 1, 1);
    prep_all<<<dim3(2432), blk, 0, stream>>>(x, w1, w2, qw, kw, vw, ow,
                                             xk, w1f, w2f, qwf, kwf, vwf, owf);

    conv_k<0><<<dim3(1024), blk, 0, stream>>>(w1f, xk, cb1, g1, be1, mu1, va1, (void*)y1k);
    conv_k<1><<<dim3(1024), blk, 0, stream>>>(w2f, y1k, cb2, g2, be2, mu2, va2, (void*)c2);
    // q pre-scaled by log2(e)/sqrt(32) for exp2-domain softmax
    qkv_k<<<dim3(1536), blk, 0, stream>>>(qwf, kwf, vwf, xk, qb_, kb_, vb_,
                                          qT, kT, vbuf, 0.2550392430300696f);
    attn_kernel<<<dim3(2048), blk, 0, stream>>>(qT, kT, vbuf, attnk);
    fi_k<<<dim3(1024), blk, 0, stream>>>(owf, attnk, ob_, c2, x, gate, (float*)d_out);

    (void)in_sizes; (void)n_in; (void)out_size; (void)ws_size;
}

// Round 10
// 258.613 us; speedup vs baseline: 1.2017x; 1.2017x over previous
//
#include <hip/hip_runtime.h>
#include <hip/hip_bf16.h>

using bf16 = __hip_bfloat16;
typedef __attribute__((ext_vector_type(4))) float floatx4;
typedef __attribute__((ext_vector_type(8))) __bf16 bf16x8;
typedef __attribute__((ext_vector_type(4))) __bf16 bf16x4;

#define LGKM_WAIT() asm volatile("s_waitcnt lgkmcnt(0)" ::: "memory")

// ---------------------------------------------------------------------------
// Weight prep: fp32 [O=256][K=256][taps] -> bf16 frag-ordered
// [t][kc][o 0..255][kk 0..31]
// ---------------------------------------------------------------------------
__device__ __forceinline__ void prep_one(const float* __restrict__ src,
                                         bf16* __restrict__ dst, int idx, int ntaps)
{
    const int kk = idx & 31, o = (idx >> 5) & 255, kc = (idx >> 13) & 7, t = idx >> 16;
    dst[idx] = __float2bfloat16(src[(o * 256 + kc * 32 + kk) * ntaps + t]);
}

__global__ __launch_bounds__(256) void prep_all(
    const float* __restrict__ x,
    const float* __restrict__ w1, const float* __restrict__ w2,
    const float* __restrict__ qw, const float* __restrict__ kw,
    const float* __restrict__ vw, const float* __restrict__ ow,
    bf16* __restrict__ xk, bf16* __restrict__ w1f, bf16* __restrict__ w2f,
    bf16* __restrict__ qwf, bf16* __restrict__ kwf,
    bf16* __restrict__ vwf, bf16* __restrict__ owf)
{
    __shared__ float T[64][65];
    const int blk = blockIdx.x, tid = threadIdx.x;
    if (blk < 1024) {
        const int n0 = (blk & 15) * 64, c0 = ((blk >> 4) & 3) * 64, b = blk >> 6;
        #pragma unroll
        for (int it = 0; it < 4; ++it) {
            const int tau = tid + it * 256;
            const int c = tau >> 4, seg = tau & 15;
            const float4 vv = *(const float4*)&x[((b * 256 + c0 + c) << 10) + n0 + seg * 4];
            T[seg * 4 + 0][c] = vv.x; T[seg * 4 + 1][c] = vv.y;
            T[seg * 4 + 2][c] = vv.z; T[seg * 4 + 3][c] = vv.w;
        }
        __syncthreads();
        #pragma unroll
        for (int it = 0; it < 2; ++it) {
            const int tau = tid + it * 256;
            const int n = tau >> 3, seg = tau & 7;
            bf16x8 o8;
            #pragma unroll
            for (int q = 0; q < 8; ++q) o8[q] = (__bf16)T[n][seg * 8 + q];
            const int c = c0 + seg * 8;
            *(bf16x8*)&xk[((((b << 3) + (c >> 5)) << 10) + n0 + n) * 32 + (c & 31)] = o8;
        }
    } else if (blk < 2176) {
        const int base = (blk - 1024) * 256 + tid;
        #pragma unroll
        for (int k = 0; k < 4; ++k) {
            const int idx = base + k * 294912;
            if (idx < 589824) prep_one(w1, w1f, idx, 9);
            else              prep_one(w2, w2f, idx - 589824, 9);
        }
    } else {
        const int r = (blk - 2176) * 256 + tid;
        prep_one(qw, qwf, r, 1);
        prep_one(kw, kwf, r, 1);
        prep_one(vw, vwf, r, 1);
        prep_one(ow, owf, r, 1);
    }
}

// ---------------------------------------------------------------------------
// Conv3x3 GEMM (r8 config): double-buffered LDS halo tile (6x34 rows, pad 40),
// one barrier per kc; per kc prefetch kc+1 globals->regs during compute.
// Block 128sp x 64oc, waves 2x2 (64sp x 32oc, acc[4][2]); grid (8,4,16).
// MODE 0: BN+ReLU -> bf16 k-blocked | MODE 1: BN -> fp32 c-major (repacked)
// ---------------------------------------------------------------------------
template<int MODE>
__global__ __launch_bounds__(256) void conv_k(
    const bf16* __restrict__ Wf, const bf16* __restrict__ Act,
    const float* __restrict__ bias,
    const float* __restrict__ gam, const float* __restrict__ bet,
    const float* __restrict__ mu, const float* __restrict__ var,
    void* __restrict__ outp)
{
    __shared__ __align__(16) unsigned char smb[34816];  // 2x16320 staging; repack alias

    const int bn = blockIdx.x, bo = blockIdx.y, b = blockIdx.z;
    const int tid = threadIdx.x;
    const int wave = tid >> 6, lane = tid & 63;
    const int quad = lane >> 4, l16 = lane & 15;
    const int wm = wave & 1, wn = wave >> 1;

    // staging geometry: 204 halo rows (6y x 34x) x 4 chunks = 816 slots
    int srow[4], scol[4], sn[4]; bool sval[4];
    #pragma unroll
    for (int it = 0; it < 4; ++it) {
        const int s = tid + it * 256;
        const int row = s >> 2;
        const int yi = row / 34, x34 = row - yi * 34;
        const int gy = bn * 4 - 1 + yi, gx = x34 - 1;
        sval[it] = (s < 816) & (gy >= 0) & (gy < 32) & (gx >= 0) & (gx < 32);
        sn[it] = (gy << 5) + gx;
        srow[it] = row; scol[it] = (s & 3) * 8;
    }

    const bf16* __restrict__ act0 = Act + ((size_t)b << 18);
    bf16x8 rg[4];
    #pragma unroll
    for (int it = 0; it < 4; ++it) {
        bf16x8 v = {};
        if (sval[it]) v = *(const bf16x8*)&act0[sn[it] * 32 + scol[it]];
        rg[it] = v;
    }
    {
        bf16* st = (bf16*)smb;
        #pragma unroll
        for (int it = 0; it < 4; ++it)
            if (tid + it * 256 < 816) *(bf16x8*)&st[srow[it] * 40 + scol[it]] = rg[it];
    }
    __syncthreads();

    floatx4 acc[4][2] = {};

    for (int kc = 0; kc < 8; ++kc) {
        if (kc < 7) {
            const bf16* __restrict__ actn = act0 + ((kc + 1) << 15);
            #pragma unroll
            for (int it = 0; it < 4; ++it) {
                bf16x8 v = {};
                if (sval[it]) v = *(const bf16x8*)&actn[sn[it] * 32 + scol[it]];
                rg[it] = v;
            }
        }
        const bf16* __restrict__ cur = (const bf16*)(smb + (kc & 1) * 16320);
        #pragma unroll
        for (int t = 0; t < 9; ++t) {
            const int dy = t / 3 - 1, dx = t % 3 - 1;
            bf16x8 af[4], wf[2];
            #pragma unroll
            for (int p = 0; p < 4; ++p) {
                const int m = wm * 64 + p * 16 + l16;
                const int row = ((m >> 5) + 1 + dy) * 34 + ((m & 31) + 1 + dx);
                af[p] = *(const bf16x8*)&cur[row * 40 + quad * 8];
            }
            #pragma unroll
            for (int p = 0; p < 2; ++p)
                wf[p] = *(const bf16x8*)&Wf[((((t * 8 + kc) << 8) + bo * 64 + wn * 32 + p * 16 + l16) << 5) + quad * 8];
            #pragma unroll
            for (int i = 0; i < 4; ++i)
                #pragma unroll
                for (int j = 0; j < 2; ++j)
                    acc[i][j] = __builtin_amdgcn_mfma_f32_16x16x32_bf16(af[i], wf[j], acc[i][j], 0, 0, 0);
        }
        if (kc < 7) {
            bf16* nxt = (bf16*)(smb + ((kc + 1) & 1) * 16320);
            #pragma unroll
            for (int it = 0; it < 4; ++it)
                if (tid + it * 256 < 816) *(bf16x8*)&nxt[srow[it] * 40 + scol[it]] = rg[it];
        }
        __syncthreads();
    }

    if constexpr (MODE == 0) {
        // bf16 k-blocked out [b][oc>>5][n][oc&31]; per-wave repack [n 64][40]
        bf16* rp = (bf16*)(smb + wave * 5120);
        #pragma unroll
        for (int i = 0; i < 4; ++i)
            #pragma unroll
            for (int j = 0; j < 2; ++j) {
                const int oc = bo * 64 + wn * 32 + j * 16 + l16;
                const float inv = gam[oc] * rsqrtf(var[oc] + 1e-5f);
                const float sh = bet[oc] - mu[oc] * inv;
                const float bs = bias[oc];
                #pragma unroll
                for (int r = 0; r < 4; ++r) {
                    const float v = (acc[i][j][r] + bs) * inv + sh;
                    rp[(i * 16 + quad * 4 + r) * 40 + j * 16 + l16] =
                        __float2bfloat16(v < 0.0f ? 0.0f : v);
                }
            }
        LGKM_WAIT();
        const int kc2 = bo * 2 + wn;
        bf16* dst = (bf16*)outp + ((((size_t)b << 3) + kc2) << 15) + (bn * 128 + wm * 64) * 32;
        #pragma unroll
        for (int it = 0; it < 4; ++it) {
            const int s = it * 64 + lane;
            const int nl = s >> 2, cp = (s & 3) * 8;
            *(bf16x8*)&dst[nl * 32 + cp] = *(const bf16x8*)&rp[nl * 40 + cp];
        }
    } else {
        // fp32 c-major out; per-wave repack [oc 32][68]
        float* rp = (float*)(smb + wave * 8704);
        #pragma unroll
        for (int i = 0; i < 4; ++i)
            #pragma unroll
            for (int j = 0; j < 2; ++j) {
                const int oc = bo * 64 + wn * 32 + j * 16 + l16;
                const float inv = gam[oc] * rsqrtf(var[oc] + 1e-5f);
                const float sh = bet[oc] - mu[oc] * inv;
                const float bs = bias[oc];
                float4 o;
                o.x = (acc[i][j][0] + bs) * inv + sh;
                o.y = (acc[i][j][1] + bs) * inv + sh;
                o.z = (acc[i][j][2] + bs) * inv + sh;
                o.w = (acc[i][j][3] + bs) * inv + sh;
                *(float4*)&rp[(j * 16 + l16) * 68 + i * 16 + quad * 4] = o;
            }
        LGKM_WAIT();
        const int n0 = bn * 128 + wm * 64;
        #pragma unroll
        for (int it = 0; it < 8; ++it) {
            const int s = it * 64 + lane;
            const int ocl = s >> 4, nch = s & 15;
            const int oc = bo * 64 + wn * 32 + ocl;
            float4 v = *(const float4*)&rp[ocl * 68 + nch * 4];
            *(float4*)&((float*)outp)[((b * 256 + oc) << 10) + n0 + nch * 4] = v;
        }
    }
}

// ---------------------------------------------------------------------------
// Fused q/k/v projections (r8 config), barrier-free mainloop, per-wave LDS
// repack stores. Grid (8,12,16): sel=by>>2: 0:q,1:k,2:v.
// q pre-scaled by log2(e)/sqrt(32) for the exp2 softmax path.
// ---------------------------------------------------------------------------
__global__ __launch_bounds__(256) void qkv_k(
    const bf16* __restrict__ Wq, const bf16* __restrict__ Wk, const bf16* __restrict__ Wv,
    const bf16* __restrict__ Act,
    const float* __restrict__ bq, const float* __restrict__ bk, const float* __restrict__ bv,
    bf16* __restrict__ Oq, bf16* __restrict__ Ok, bf16* __restrict__ Ov, float qscale)
{
    __shared__ __align__(16) unsigned char qsm[20480];
    const int bn = blockIdx.x, by = blockIdx.y, b = blockIdx.z;
    const int sel = by >> 2, bo = by & 3;
    const bf16* __restrict__ Wf = (sel == 0) ? Wq : (sel == 1) ? Wk : Wv;
    const float* __restrict__ bias = (sel == 0) ? bq : (sel == 1) ? bk : bv;
    const float scale = (sel == 0) ? qscale : 1.0f;

    const int tid = threadIdx.x;
    const int wave = tid >> 6, lane = tid & 63;
    const int quad = lane >> 4, l16 = lane & 15;
    const int wm = wave & 1, wn = wave >> 1;

    floatx4 acc[4][2] = {};

    for (int kc = 0; kc < 8; ++kc) {
        const bf16* __restrict__ actk = Act + ((size_t)b << 18) + (kc << 15);
        bf16x8 af[4], wf[2];
        #pragma unroll
        for (int p = 0; p < 4; ++p)
            af[p] = *(const bf16x8*)&actk[(bn * 128 + wm * 64 + p * 16 + l16) * 32 + quad * 8];
        #pragma unroll
        for (int p = 0; p < 2; ++p)
            wf[p] = *(const bf16x8*)&Wf[(((kc << 8) + bo * 64 + wn * 32 + p * 16 + l16) << 5) + quad * 8];
        #pragma unroll
        for (int i = 0; i < 4; ++i)
            #pragma unroll
            for (int j = 0; j < 2; ++j)
                acc[i][j] = __builtin_amdgcn_mfma_f32_16x16x32_bf16(af[i], wf[j], acc[i][j], 0, 0, 0);
    }

    if (sel < 2) {
        bf16* rp = (bf16*)(qsm + wave * 5120);   // [n_local 64][40]
        #pragma unroll
        for (int i = 0; i < 4; ++i)
            #pragma unroll
            for (int j = 0; j < 2; ++j) {
                const int oc = bo * 64 + wn * 32 + j * 16 + l16;
                const float bs = bias[oc];
                #pragma unroll
                for (int r = 0; r < 4; ++r)
                    rp[(i * 16 + quad * 4 + r) * 40 + j * 16 + l16] =
                        __float2bfloat16((acc[i][j][r] + bs) * scale);
            }
        LGKM_WAIT();
        bf16* __restrict__ outp = (sel == 0) ? Oq : Ok;
        const int h = bo * 2 + wn;
        bf16* dst = outp + ((((size_t)b << 3) + h) << 15) + (bn * 128 + wm * 64) * 32;
        #pragma unroll
        for (int it = 0; it < 4; ++it) {
            const int s = it * 64 + lane;
            const int nl = s >> 2, cp = (s & 3) * 8;
            *(bf16x8*)&dst[nl * 32 + cp] = *(const bf16x8*)&rp[nl * 40 + cp];
        }
    } else {
        bf16* rp = (bf16*)(qsm + wave * 4608);   // [oc 32][72]
        #pragma unroll
        for (int i = 0; i < 4; ++i)
            #pragma unroll
            for (int j = 0; j < 2; ++j) {
                const int oc = bo * 64 + wn * 32 + j * 16 + l16;
                const float bs = bias[oc];
                bf16x4 o4;
                #pragma unroll
                for (int r = 0; r < 4; ++r) o4[r] = (__bf16)(acc[i][j][r] + bs);
                *(bf16x4*)&rp[(j * 16 + l16) * 72 + i * 16 + quad * 4] = o4;
            }
        LGKM_WAIT();
        const int n0 = bn * 128 + wm * 64;
        #pragma unroll
        for (int it = 0; it < 4; ++it) {
            const int s = it * 64 + lane;
            const int ocl = s >> 3, nch = s & 7;
            const int oc = bo * 64 + wn * 32 + ocl;
            *(bf16x8*)&Ov[((b * 256 + oc) << 10) + n0 + nch * 8] =
                *(const bf16x8*)&rp[ocl * 72 + nch * 8];
        }
    }
}

// ---------------------------------------------------------------------------
// Flash attention (r8 geometry + r9 winners): S^T = K Q^T, 32 q/wave,
// 1024 blocks; XCD swizzle h = L&7 (per-XCD head affinity -> K/V L2-resident,
// FETCH 69.7->12.3 MB measured r9); exp2-domain softmax (q pre-scaled).
// Per-wave P in LDS; no barriers.
// ---------------------------------------------------------------------------
__global__ __launch_bounds__(256) void attn_kernel(
    const bf16* __restrict__ Q, const bf16* __restrict__ K,
    const bf16* __restrict__ V, bf16* __restrict__ O)
{
    __shared__ __align__(16) bf16 Pl[4][32][136];  // [wave][q_local][key]

    const int L = blockIdx.x;
    const int h = L & 7, slot = L >> 3;
    const int b = slot & 15, qb = slot >> 4;       // qb 0..7
    const int tid = threadIdx.x;
    const int wave = tid >> 6, lane = tid & 63;
    const int quad = lane >> 4, l16 = lane & 15;

    const bf16* __restrict__ Qh = Q + ((((size_t)b << 3) + h) << 15);
    const bf16* __restrict__ Kh = K + ((((size_t)b << 3) + h) << 15);
    const int qrow0 = qb * 128 + wave * 32;

    bf16x8 qf[2];
    #pragma unroll
    for (int i = 0; i < 2; ++i)
        qf[i] = *(const bf16x8*)&Qh[(qrow0 + i * 16 + l16) * 32 + quad * 8];

    float lp[2] = {0.0f, 0.0f};
    floatx4 oacc[2][2] = {};

    for (int kt = 0; kt < 8; ++kt) {
        bf16x8 kf[8];
        #pragma unroll
        for (int kb = 0; kb < 8; ++kb)
            kf[kb] = *(const bf16x8*)&Kh[(kt * 128 + kb * 16 + l16) * 32 + quad * 8];
        bf16x8 vb[2][4];
        #pragma unroll
        for (int jd = 0; jd < 2; ++jd)
            #pragma unroll
            for (int kk = 0; kk < 4; ++kk)
                vb[jd][kk] = *(const bf16x8*)&V[((b * 256 + h * 32 + jd * 16 + l16) << 10)
                                               + kt * 128 + kk * 32 + quad * 8];

        // S^T: D[row=key=kb*16+quad*4+r][col=q=i*16+l16]; p = 2^s
        #pragma unroll
        for (int kb = 0; kb < 8; ++kb) {
            #pragma unroll
            for (int i = 0; i < 2; ++i) {
                floatx4 zz = {0.f, 0.f, 0.f, 0.f};
                floatx4 st = __builtin_amdgcn_mfma_f32_16x16x32_bf16(kf[kb], qf[i], zz, 0, 0, 0);
                const float e0 = __builtin_amdgcn_exp2f(st[0]);
                const float e1 = __builtin_amdgcn_exp2f(st[1]);
                const float e2 = __builtin_amdgcn_exp2f(st[2]);
                const float e3 = __builtin_amdgcn_exp2f(st[3]);
                lp[i] += (e0 + e1) + (e2 + e3);
                bf16x4 p4 = {(__bf16)e0, (__bf16)e1, (__bf16)e2, (__bf16)e3};
                *(bf16x4*)&Pl[wave][i * 16 + l16][kb * 16 + quad * 4] = p4;
            }
        }

        // O += V P : A[m=d][k=key], B[k=key][n=q]
        #pragma unroll
        for (int kk = 0; kk < 4; ++kk) {
            bf16x8 pf[2];
            #pragma unroll
            for (int i = 0; i < 2; ++i)
                pf[i] = *(const bf16x8*)&Pl[wave][i * 16 + l16][kk * 32 + quad * 8];
            #pragma unroll
            for (int jd = 0; jd < 2; ++jd)
                #pragma unroll
                for (int i = 0; i < 2; ++i)
                    oacc[jd][i] = __builtin_amdgcn_mfma_f32_16x16x32_bf16(
                        vb[jd][kk], pf[i], oacc[jd][i], 0, 0, 0);
        }
    }

    bf16* __restrict__ Oh = O + ((((size_t)b << 3) + h) << 15);
    #pragma unroll
    for (int i = 0; i < 2; ++i) {
        float l = lp[i];
        l += __shfl_xor(l, 16, 64);
        l += __shfl_xor(l, 32, 64);
        const float inv = 1.0f / l;
        const int qn = qrow0 + i * 16 + l16;
        #pragma unroll
        for (int jd = 0; jd < 2; ++jd) {
            bf16x4 o4;
            #pragma unroll
            for (int r = 0; r < 4; ++r) o4[r] = (__bf16)(oacc[jd][i][r] * inv);
            *(bf16x4*)&Oh[qn * 32 + jd * 16 + quad * 4] = o4;
        }
    }
}

// ---------------------------------------------------------------------------
// Final: out = relu(c2 + sigmoid(gate)*(ow@attn + ob) + x), fp32 c-major.
// (r8 config) Barrier-free mainloop; per-wave LDS repack epilogue.
// ---------------------------------------------------------------------------
__global__ __launch_bounds__(256) void fi_k(
    const bf16* __restrict__ Wf, const bf16* __restrict__ Act,
    const float* __restrict__ bias,
    const float* __restrict__ c2, const float* __restrict__ resid,
    const float* __restrict__ gate, float* __restrict__ outp)
{
    __shared__ __align__(16) unsigned char fsm[34816];
    const int bn = blockIdx.x, bo = blockIdx.y, b = blockIdx.z;
    const int tid = threadIdx.x;
    const int wave = tid >> 6, lane = tid & 63;
    const int quad = lane >> 4, l16 = lane & 15;
    const int wm = wave & 1, wn = wave >> 1;

    floatx4 acc[4][2] = {};

    for (int kc = 0; kc < 8; ++kc) {
        const bf16* __restrict__ actk = Act + ((size_t)b << 18) + (kc << 15);
        bf16x8 af[4], wf[2];
        #pragma unroll
        for (int p = 0; p < 4; ++p)
            af[p] = *(const bf16x8*)&actk[(bn * 128 + wm * 64 + p * 16 + l16) * 32 + quad * 8];
        #pragma unroll
        for (int p = 0; p < 2; ++p)
            wf[p] = *(const bf16x8*)&Wf[(((kc << 8) + bo * 64 + wn * 32 + p * 16 + l16) << 5) + quad * 8];
        #pragma unroll
        for (int i = 0; i < 4; ++i)
            #pragma unroll
            for (int j = 0; j < 2; ++j)
                acc[i][j] = __builtin_amdgcn_mfma_f32_16x16x32_bf16(af[i], wf[j], acc[i][j], 0, 0, 0);
    }

    const float sg = 1.0f / (1.0f + __expf(-gate[0]));

    float* rp = (float*)(fsm + wave * 8704);   // [oc 32][68]
    #pragma unroll
    for (int i = 0; i < 4; ++i)
        #pragma unroll
        for (int j = 0; j < 2; ++j) {
            const int oc = bo * 64 + wn * 32 + j * 16 + l16;
            const float bs = bias[oc];
            float4 o;
            o.x = acc[i][j][0] + bs; o.y = acc[i][j][1] + bs;
            o.z = acc[i][j][2] + bs; o.w = acc[i][j][3] + bs;
            *(float4*)&rp[(j * 16 + l16) * 68 + i * 16 + quad * 4] = o;
        }
    LGKM_WAIT();
    const int n0 = bn * 128 + wm * 64;
    #pragma unroll
    for (int it = 0; it < 8; ++it) {
        const int s = it * 64 + lane;
        const int ocl = s >> 4, nch = s & 15;
        const int oc = bo * 64 + wn * 32 + ocl;
        const int idx = ((b * 256 + oc) << 10) + n0 + nch * 4;
        float4 v = *(const float4*)&rp[ocl * 68 + nch * 4];
        const float4 cc = *(const float4*)&c2[idx];
        const float4 rr = *(const float4*)&resid[idx];
        float4 o;
        o.x = cc.x + sg * v.x + rr.x; o.y = cc.y + sg * v.y + rr.y;
        o.z = cc.z + sg * v.z + rr.z; o.w = cc.w + sg * v.w + rr.w;
        o.x = o.x < 0.0f ? 0.0f : o.x; o.y = o.y < 0.0f ? 0.0f : o.y;
        o.z = o.z < 0.0f ? 0.0f : o.z; o.w = o.w < 0.0f ? 0.0f : o.w;
        *(float4*)&outp[idx] = o;
    }
}

extern "C" void kernel_launch(void* const* d_in, const int* in_sizes, int n_in,
                              void* d_out, int out_size, void* d_ws, size_t ws_size,
                              hipStream_t stream)
{
    const float* x    = (const float*)d_in[0];
    const float* w1   = (const float*)d_in[1];
    const float* cb1  = (const float*)d_in[2];
    const float* g1   = (const float*)d_in[3];
    const float* be1  = (const float*)d_in[4];
    const float* mu1  = (const float*)d_in[5];
    const float* va1  = (const float*)d_in[6];
    const float* w2   = (const float*)d_in[7];
    const float* cb2  = (const float*)d_in[8];
    const float* g2   = (const float*)d_in[9];
    const float* be2  = (const float*)d_in[10];
    const float* mu2  = (const float*)d_in[11];
    const float* va2  = (const float*)d_in[12];
    const float* qw   = (const float*)d_in[13];
    const float* qb_  = (const float*)d_in[14];
    const float* kw   = (const float*)d_in[15];
    const float* kb_  = (const float*)d_in[16];
    const float* vw   = (const float*)d_in[17];
    const float* vb_  = (const float*)d_in[18];
    const float* ow   = (const float*)d_in[19];
    const float* ob_  = (const float*)d_in[20];
    const float* gate = (const float*)d_in[21];

    char* ws = (char*)d_ws;
    bf16*  xk    = (bf16*) (ws + 0);          //  8,388,608  k-blocked x
    bf16*  y1k   = (bf16*) (ws + 8388608);    //  8,388,608  conv1 out k-blocked
    bf16*  attnk = (bf16*) (ws + 8388608);    //  reuse (y1k dead after conv2)
    float* c2    = (float*)(ws + 16777216);   // 16,777,216  conv2 out c-major fp32
    bf16*  qT    = (bf16*) (ws + 33554432);   //  8,388,608  head-blocked
    bf16*  kT    = (bf16*) (ws + 41943040);   //  8,388,608  head-blocked
    bf16*  vbuf  = (bf16*) (ws + 50331648);   //  8,388,608  c-major
    bf16*  w1f   = (bf16*) (ws + 58720256);
    bf16*  w2f   = (bf16*) (ws + 59899904);
    bf16*  qwf   = (bf16*) (ws + 61079552);
    bf16*  kwf   = (bf16*) (ws + 61210624);
    bf16*  vwf   = (bf16*) (ws + 61341696);
    bf16*  owf   = (bf16*) (ws + 61472768);

    dim3 blk(256, 1, 1);
    prep_all<<<dim3(2432), blk, 0, stream>>>(x, w1, w2, qw, kw, vw, ow,
                                             xk, w1f, w2f, qwf, kwf, vwf, owf);

    dim3 gg(8, 4, 16);
    conv_k<0><<<gg, blk, 0, stream>>>(w1f, xk, cb1, g1, be1, mu1, va1, (void*)y1k);
    conv_k<1><<<gg, blk, 0, stream>>>(w2f, y1k, cb2, g2, be2, mu2, va2, (void*)c2);
    // q pre-scaled by log2(e)/sqrt(32) for exp2-domain softmax
    qkv_k<<<dim3(8, 12, 16), blk, 0, stream>>>(qwf, kwf, vwf, xk, qb_, kb_, vb_,
                                               qT, kT, vbuf, 0.2550392430300696f);
    attn_kernel<<<dim3(1024), blk, 0, stream>>>(qT, kT, vbuf, attnk);
    fi_k<<<gg, blk, 0, stream>>>(owf, attnk, ob_, c2, x, gate, (float*)d_out);

    (void)in_sizes; (void)n_in; (void)out_size; (void)ws_size;
}

// Round 11
// 241.610 us; speedup vs baseline: 1.2862x; 1.0704x over previous
//
#include <hip/hip_runtime.h>
#include <hip/hip_bf16.h>

using bf16 = __hip_bfloat16;
typedef __attribute__((ext_vector_type(4))) float floatx4;
typedef __attribute__((ext_vector_type(8))) __bf16 bf16x8;
typedef __attribute__((ext_vector_type(4))) __bf16 bf16x4;

#define LGKM_WAIT() asm volatile("s_waitcnt lgkmcnt(0)" ::: "memory")

// ---------------------------------------------------------------------------
// Weight prep: fp32 [O=256][K=256][taps] -> bf16 frag-ordered
// [t][kc][o 0..255][kk 0..31]
// ---------------------------------------------------------------------------
__device__ __forceinline__ void prep_one(const float* __restrict__ src,
                                         bf16* __restrict__ dst, int idx, int ntaps)
{
    const int kk = idx & 31, o = (idx >> 5) & 255, kc = (idx >> 13) & 7, t = idx >> 16;
    dst[idx] = __float2bfloat16(src[(o * 256 + kc * 32 + kk) * ntaps + t]);
}

__global__ __launch_bounds__(256) void prep_all(
    const float* __restrict__ x,
    const float* __restrict__ w1, const float* __restrict__ w2,
    const float* __restrict__ qw, const float* __restrict__ kw,
    const float* __restrict__ vw, const float* __restrict__ ow,
    bf16* __restrict__ xk, bf16* __restrict__ w1f, bf16* __restrict__ w2f,
    bf16* __restrict__ qwf, bf16* __restrict__ kwf,
    bf16* __restrict__ vwf, bf16* __restrict__ owf)
{
    __shared__ float T[64][65];
    const int blk = blockIdx.x, tid = threadIdx.x;
    if (blk < 1024) {
        const int n0 = (blk & 15) * 64, c0 = ((blk >> 4) & 3) * 64, b = blk >> 6;
        #pragma unroll
        for (int it = 0; it < 4; ++it) {
            const int tau = tid + it * 256;
            const int c = tau >> 4, seg = tau & 15;
            const float4 vv = *(const float4*)&x[((b * 256 + c0 + c) << 10) + n0 + seg * 4];
            T[seg * 4 + 0][c] = vv.x; T[seg * 4 + 1][c] = vv.y;
            T[seg * 4 + 2][c] = vv.z; T[seg * 4 + 3][c] = vv.w;
        }
        __syncthreads();
        #pragma unroll
        for (int it = 0; it < 2; ++it) {
            const int tau = tid + it * 256;
            const int n = tau >> 3, seg = tau & 7;
            bf16x8 o8;
            #pragma unroll
            for (int q = 0; q < 8; ++q) o8[q] = (__bf16)T[n][seg * 8 + q];
            const int c = c0 + seg * 8;
            *(bf16x8*)&xk[((((b << 3) + (c >> 5)) << 10) + n0 + n) * 32 + (c & 31)] = o8;
        }
    } else if (blk < 2176) {
        const int base = (blk - 1024) * 256 + tid;
        #pragma unroll
        for (int k = 0; k < 4; ++k) {
            const int idx = base + k * 294912;
            if (idx < 589824) prep_one(w1, w1f, idx, 9);
            else              prep_one(w2, w2f, idx - 589824, 9);
        }
    } else {
        const int r = (blk - 2176) * 256 + tid;
        prep_one(qw, qwf, r, 1);
        prep_one(kw, kwf, r, 1);
        prep_one(vw, vwf, r, 1);
        prep_one(ow, owf, r, 1);
    }
}

// ---------------------------------------------------------------------------
// Conv3x3 GEMM body (r8 config): double-buffered LDS halo tile (6x34, pad 40),
// one barrier per kc, act prefetch. 128sp x 64oc, waves 2x2, acc[4][2].
// MODE 0: BN+ReLU -> bf16 k-blocked | MODE 1: BN -> fp32 c-major (repacked)
// ---------------------------------------------------------------------------
template<int MODE>
__device__ __forceinline__ void conv_body(
    unsigned char* smb, int bn, int bo, int b,
    const bf16* __restrict__ Wf, const bf16* __restrict__ Act,
    const float* __restrict__ bias,
    const float* __restrict__ gam, const float* __restrict__ bet,
    const float* __restrict__ mu, const float* __restrict__ var,
    void* __restrict__ outp)
{
    const int tid = threadIdx.x;
    const int wave = tid >> 6, lane = tid & 63;
    const int quad = lane >> 4, l16 = lane & 15;
    const int wm = wave & 1, wn = wave >> 1;

    int srow[4], scol[4], sn[4]; bool sval[4];
    #pragma unroll
    for (int it = 0; it < 4; ++it) {
        const int s = tid + it * 256;
        const int row = s >> 2;
        const int yi = row / 34, x34 = row - yi * 34;
        const int gy = bn * 4 - 1 + yi, gx = x34 - 1;
        sval[it] = (s < 816) & (gy >= 0) & (gy < 32) & (gx >= 0) & (gx < 32);
        sn[it] = (gy << 5) + gx;
        srow[it] = row; scol[it] = (s & 3) * 8;
    }

    const bf16* __restrict__ act0 = Act + ((size_t)b << 18);
    bf16x8 rg[4];
    #pragma unroll
    for (int it = 0; it < 4; ++it) {
        bf16x8 v = {};
        if (sval[it]) v = *(const bf16x8*)&act0[sn[it] * 32 + scol[it]];
        rg[it] = v;
    }
    {
        bf16* st = (bf16*)smb;
        #pragma unroll
        for (int it = 0; it < 4; ++it)
            if (tid + it * 256 < 816) *(bf16x8*)&st[srow[it] * 40 + scol[it]] = rg[it];
    }
    __syncthreads();

    floatx4 acc[4][2] = {};

    for (int kc = 0; kc < 8; ++kc) {
        if (kc < 7) {
            const bf16* __restrict__ actn = act0 + ((kc + 1) << 15);
            #pragma unroll
            for (int it = 0; it < 4; ++it) {
                bf16x8 v = {};
                if (sval[it]) v = *(const bf16x8*)&actn[sn[it] * 32 + scol[it]];
                rg[it] = v;
            }
        }
        const bf16* __restrict__ cur = (const bf16*)(smb + (kc & 1) * 16320);
        #pragma unroll
        for (int t = 0; t < 9; ++t) {
            const int dy = t / 3 - 1, dx = t % 3 - 1;
            bf16x8 af[4], wf[2];
            #pragma unroll
            for (int p = 0; p < 4; ++p) {
                const int m = wm * 64 + p * 16 + l16;
                const int row = ((m >> 5) + 1 + dy) * 34 + ((m & 31) + 1 + dx);
                af[p] = *(const bf16x8*)&cur[row * 40 + quad * 8];
            }
            #pragma unroll
            for (int p = 0; p < 2; ++p)
                wf[p] = *(const bf16x8*)&Wf[((((t * 8 + kc) << 8) + bo * 64 + wn * 32 + p * 16 + l16) << 5) + quad * 8];
            #pragma unroll
            for (int i = 0; i < 4; ++i)
                #pragma unroll
                for (int j = 0; j < 2; ++j)
                    acc[i][j] = __builtin_amdgcn_mfma_f32_16x16x32_bf16(af[i], wf[j], acc[i][j], 0, 0, 0);
        }
        if (kc < 7) {
            bf16* nxt = (bf16*)(smb + ((kc + 1) & 1) * 16320);
            #pragma unroll
            for (int it = 0; it < 4; ++it)
                if (tid + it * 256 < 816) *(bf16x8*)&nxt[srow[it] * 40 + scol[it]] = rg[it];
        }
        __syncthreads();
    }

    if constexpr (MODE == 0) {
        bf16* rp = (bf16*)(smb + wave * 5120);   // [n 64][40]
        #pragma unroll
        for (int i = 0; i < 4; ++i)
            #pragma unroll
            for (int j = 0; j < 2; ++j) {
                const int oc = bo * 64 + wn * 32 + j * 16 + l16;
                const float inv = gam[oc] * rsqrtf(var[oc] + 1e-5f);
                const float sh = bet[oc] - mu[oc] * inv;
                const float bs = bias[oc];
                #pragma unroll
                for (int r = 0; r < 4; ++r) {
                    const float v = (acc[i][j][r] + bs) * inv + sh;
                    rp[(i * 16 + quad * 4 + r) * 40 + j * 16 + l16] =
                        __float2bfloat16(v < 0.0f ? 0.0f : v);
                }
            }
        LGKM_WAIT();
        const int kc2 = bo * 2 + wn;
        bf16* dst = (bf16*)outp + ((((size_t)b << 3) + kc2) << 15) + (bn * 128 + wm * 64) * 32;
        #pragma unroll
        for (int it = 0; it < 4; ++it) {
            const int s = it * 64 + lane;
            const int nl = s >> 2, cp = (s & 3) * 8;
            *(bf16x8*)&dst[nl * 32 + cp] = *(const bf16x8*)&rp[nl * 40 + cp];
        }
    } else {
        float* rp = (float*)(smb + wave * 8704);   // [oc 32][68]
        #pragma unroll
        for (int i = 0; i < 4; ++i)
            #pragma unroll
            for (int j = 0; j < 2; ++j) {
                const int oc = bo * 64 + wn * 32 + j * 16 + l16;
                const float inv = gam[oc] * rsqrtf(var[oc] + 1e-5f);
                const float sh = bet[oc] - mu[oc] * inv;
                const float bs = bias[oc];
                float4 o;
                o.x = (acc[i][j][0] + bs) * inv + sh;
                o.y = (acc[i][j][1] + bs) * inv + sh;
                o.z = (acc[i][j][2] + bs) * inv + sh;
                o.w = (acc[i][j][3] + bs) * inv + sh;
                *(float4*)&rp[(j * 16 + l16) * 68 + i * 16 + quad * 4] = o;
            }
        LGKM_WAIT();
        const int n0 = bn * 128 + wm * 64;
        #pragma unroll
        for (int it = 0; it < 8; ++it) {
            const int s = it * 64 + lane;
            const int ocl = s >> 4, nch = s & 15;
            const int oc = bo * 64 + wn * 32 + ocl;
            float4 v = *(const float4*)&rp[ocl * 68 + nch * 4];
            *(float4*)&((float*)outp)[((b * 256 + oc) << 10) + n0 + nch * 4] = v;
        }
    }
}

// ---------------------------------------------------------------------------
// q/k/v projection body (barrier-free mainloop, per-wave LDS repack stores).
// sel: 0:q (scaled), 1:k, 2:v.
// ---------------------------------------------------------------------------
__device__ __forceinline__ void qkv_body(
    unsigned char* qsm, int bn, int by, int b,
    const bf16* __restrict__ Wq, const bf16* __restrict__ Wk, const bf16* __restrict__ Wv,
    const bf16* __restrict__ Act,
    const float* __restrict__ bq, const float* __restrict__ bk, const float* __restrict__ bv,
    bf16* __restrict__ Oq, bf16* __restrict__ Ok, bf16* __restrict__ Ov, float qscale)
{
    const int sel = by >> 2, bo = by & 3;
    const bf16* __restrict__ Wf = (sel == 0) ? Wq : (sel == 1) ? Wk : Wv;
    const float* __restrict__ bias = (sel == 0) ? bq : (sel == 1) ? bk : bv;
    const float scale = (sel == 0) ? qscale : 1.0f;

    const int tid = threadIdx.x;
    const int wave = tid >> 6, lane = tid & 63;
    const int quad = lane >> 4, l16 = lane & 15;
    const int wm = wave & 1, wn = wave >> 1;

    floatx4 acc[4][2] = {};

    for (int kc = 0; kc < 8; ++kc) {
        const bf16* __restrict__ actk = Act + ((size_t)b << 18) + (kc << 15);
        bf16x8 af[4], wf[2];
        #pragma unroll
        for (int p = 0; p < 4; ++p)
            af[p] = *(const bf16x8*)&actk[(bn * 128 + wm * 64 + p * 16 + l16) * 32 + quad * 8];
        #pragma unroll
        for (int p = 0; p < 2; ++p)
            wf[p] = *(const bf16x8*)&Wf[(((kc << 8) + bo * 64 + wn * 32 + p * 16 + l16) << 5) + quad * 8];
        #pragma unroll
        for (int i = 0; i < 4; ++i)
            #pragma unroll
            for (int j = 0; j < 2; ++j)
                acc[i][j] = __builtin_amdgcn_mfma_f32_16x16x32_bf16(af[i], wf[j], acc[i][j], 0, 0, 0);
    }

    if (sel < 2) {
        bf16* rp = (bf16*)(qsm + wave * 5120);   // [n 64][40]
        #pragma unroll
        for (int i = 0; i < 4; ++i)
            #pragma unroll
            for (int j = 0; j < 2; ++j) {
                const int oc = bo * 64 + wn * 32 + j * 16 + l16;
                const float bs = bias[oc];
                #pragma unroll
                for (int r = 0; r < 4; ++r)
                    rp[(i * 16 + quad * 4 + r) * 40 + j * 16 + l16] =
                        __float2bfloat16((acc[i][j][r] + bs) * scale);
            }
        LGKM_WAIT();
        bf16* __restrict__ outp = (sel == 0) ? Oq : Ok;
        const int h = bo * 2 + wn;
        bf16* dst = outp + ((((size_t)b << 3) + h) << 15) + (bn * 128 + wm * 64) * 32;
        #pragma unroll
        for (int it = 0; it < 4; ++it) {
            const int s = it * 64 + lane;
            const int nl = s >> 2, cp = (s & 3) * 8;
            *(bf16x8*)&dst[nl * 32 + cp] = *(const bf16x8*)&rp[nl * 40 + cp];
        }
    } else {
        bf16* rp = (bf16*)(qsm + wave * 4608);   // [oc 32][72]
        #pragma unroll
        for (int i = 0; i < 4; ++i)
            #pragma unroll
            for (int j = 0; j < 2; ++j) {
                const int oc = bo * 64 + wn * 32 + j * 16 + l16;
                const float bs = bias[oc];
                bf16x4 o4;
                #pragma unroll
                for (int r = 0; r < 4; ++r) o4[r] = (__bf16)(acc[i][j][r] + bs);
                *(bf16x4*)&rp[(j * 16 + l16) * 72 + i * 16 + quad * 4] = o4;
            }
        LGKM_WAIT();
        const int n0 = bn * 128 + wm * 64;
        #pragma unroll
        for (int it = 0; it < 4; ++it) {
            const int s = it * 64 + lane;
            const int ocl = s >> 3, nch = s & 7;
            const int oc = bo * 64 + wn * 32 + ocl;
            *(bf16x8*)&Ov[((b * 256 + oc) << 10) + n0 + nch * 8] =
                *(const bf16x8*)&rp[ocl * 72 + nch * 8];
        }
    }
}

// ---------------------------------------------------------------------------
// Flash attention body: S^T = K Q^T, 32 q/wave; XCD swizzle h = L&7;
// exp2-domain softmax (q pre-scaled by log2e/sqrt(32)). Per-wave P in LDS.
// ---------------------------------------------------------------------------
__device__ __forceinline__ void attn_body(
    unsigned char* smb, int L,
    const bf16* __restrict__ Q, const bf16* __restrict__ K,
    const bf16* __restrict__ V, bf16* __restrict__ O)
{
    bf16 (*Pl)[32][136] = (bf16 (*)[32][136])smb;   // [wave][q_local][key], 34816 B

    const int h = L & 7, slot = L >> 3;
    const int b = slot & 15, qb = slot >> 4;
    const int tid = threadIdx.x;
    const int wave = tid >> 6, lane = tid & 63;
    const int quad = lane >> 4, l16 = lane & 15;

    const bf16* __restrict__ Qh = Q + ((((size_t)b << 3) + h) << 15);
    const bf16* __restrict__ Kh = K + ((((size_t)b << 3) + h) << 15);
    const int qrow0 = qb * 128 + wave * 32;

    bf16x8 qf[2];
    #pragma unroll
    for (int i = 0; i < 2; ++i)
        qf[i] = *(const bf16x8*)&Qh[(qrow0 + i * 16 + l16) * 32 + quad * 8];

    float lp[2] = {0.0f, 0.0f};
    floatx4 oacc[2][2] = {};

    for (int kt = 0; kt < 8; ++kt) {
        bf16x8 kf[8];
        #pragma unroll
        for (int kb = 0; kb < 8; ++kb)
            kf[kb] = *(const bf16x8*)&Kh[(kt * 128 + kb * 16 + l16) * 32 + quad * 8];
        bf16x8 vb[2][4];
        #pragma unroll
        for (int jd = 0; jd < 2; ++jd)
            #pragma unroll
            for (int kk = 0; kk < 4; ++kk)
                vb[jd][kk] = *(const bf16x8*)&V[((b * 256 + h * 32 + jd * 16 + l16) << 10)
                                               + kt * 128 + kk * 32 + quad * 8];

        #pragma unroll
        for (int kb = 0; kb < 8; ++kb) {
            #pragma unroll
            for (int i = 0; i < 2; ++i) {
                floatx4 zz = {0.f, 0.f, 0.f, 0.f};
                floatx4 st = __builtin_amdgcn_mfma_f32_16x16x32_bf16(kf[kb], qf[i], zz, 0, 0, 0);
                const float e0 = __builtin_amdgcn_exp2f(st[0]);
                const float e1 = __builtin_amdgcn_exp2f(st[1]);
                const float e2 = __builtin_amdgcn_exp2f(st[2]);
                const float e3 = __builtin_amdgcn_exp2f(st[3]);
                lp[i] += (e0 + e1) + (e2 + e3);
                bf16x4 p4 = {(__bf16)e0, (__bf16)e1, (__bf16)e2, (__bf16)e3};
                *(bf16x4*)&Pl[wave][i * 16 + l16][kb * 16 + quad * 4] = p4;
            }
        }

        #pragma unroll
        for (int kk = 0; kk < 4; ++kk) {
            bf16x8 pf[2];
            #pragma unroll
            for (int i = 0; i < 2; ++i)
                pf[i] = *(const bf16x8*)&Pl[wave][i * 16 + l16][kk * 32 + quad * 8];
            #pragma unroll
            for (int jd = 0; jd < 2; ++jd)
                #pragma unroll
                for (int i = 0; i < 2; ++i)
                    oacc[jd][i] = __builtin_amdgcn_mfma_f32_16x16x32_bf16(
                        vb[jd][kk], pf[i], oacc[jd][i], 0, 0, 0);
        }
    }

    bf16* __restrict__ Oh = O + ((((size_t)b << 3) + h) << 15);
    #pragma unroll
    for (int i = 0; i < 2; ++i) {
        float l = lp[i];
        l += __shfl_xor(l, 16, 64);
        l += __shfl_xor(l, 32, 64);
        const float inv = 1.0f / l;
        const int qn = qrow0 + i * 16 + l16;
        #pragma unroll
        for (int jd = 0; jd < 2; ++jd) {
            bf16x4 o4;
            #pragma unroll
            for (int r = 0; r < 4; ++r) o4[r] = (__bf16)(oacc[jd][i][r] * inv);
            *(bf16x4*)&Oh[qn * 32 + jd * 16 + quad * 4] = o4;
        }
    }
}

// ---------------------------------------------------------------------------
// phase1: conv1 (blocks 0..511) + qkv (blocks 512..2047) — independent stages
// co-scheduled for latency overlap (m114: MFMA/VALU waves co-issue).
// ---------------------------------------------------------------------------
__global__ __launch_bounds__(256) void phase1_k(
    const bf16* __restrict__ w1f, const bf16* __restrict__ xk,
    const float* __restrict__ cb1,
    const float* __restrict__ g1, const float* __restrict__ be1,
    const float* __restrict__ mu1, const float* __restrict__ va1,
    bf16* __restrict__ y1k,
    const bf16* __restrict__ qwf, const bf16* __restrict__ kwf, const bf16* __restrict__ vwf,
    const float* __restrict__ qb_, const float* __restrict__ kb_, const float* __restrict__ vb_,
    bf16* __restrict__ qT, bf16* __restrict__ kT, bf16* __restrict__ vbuf, float qscale)
{
    __shared__ __align__(16) unsigned char smb[34816];
    const int L = blockIdx.x;
    if (L < 512) {
        const int bn = L & 7, bo = (L >> 3) & 3, b = L >> 5;
        conv_body<0>(smb, bn, bo, b, w1f, xk, cb1, g1, be1, mu1, va1, (void*)y1k);
    } else {
        const int L2 = L - 512;
        const int bn = L2 & 7, by = (L2 >> 3) % 12, b = L2 / 96;
        qkv_body(smb, bn, by, b, qwf, kwf, vwf, xk, qb_, kb_, vb_, qT, kT, vbuf, qscale);
    }
}

// ---------------------------------------------------------------------------
// phase2: conv2 (blocks 0..511) + attention (blocks 512..1535) — independent.
// ---------------------------------------------------------------------------
__global__ __launch_bounds__(256) void phase2_k(
    const bf16* __restrict__ w2f, const bf16* __restrict__ y1k,
    const float* __restrict__ cb2,
    const float* __restrict__ g2, const float* __restrict__ be2,
    const float* __restrict__ mu2, const float* __restrict__ va2,
    float* __restrict__ c2,
    const bf16* __restrict__ qT, const bf16* __restrict__ kT,
    const bf16* __restrict__ vbuf, bf16* __restrict__ attnk)
{
    __shared__ __align__(16) unsigned char smb[34816];
    const int L = blockIdx.x;
    if (L < 512) {
        const int bn = L & 7, bo = (L >> 3) & 3, b = L >> 5;
        conv_body<1>(smb, bn, bo, b, w2f, y1k, cb2, g2, be2, mu2, va2, (void*)c2);
    } else {
        attn_body(smb, L - 512, qT, kT, vbuf, attnk);
    }
}

// ---------------------------------------------------------------------------
// Final: out = relu(c2 + sigmoid(gate)*(ow@attn + ob) + x), fp32 c-major.
// ---------------------------------------------------------------------------
__global__ __launch_bounds__(256) void fi_k(
    const bf16* __restrict__ Wf, const bf16* __restrict__ Act,
    const float* __restrict__ bias,
    const float* __restrict__ c2, const float* __restrict__ resid,
    const float* __restrict__ gate, float* __restrict__ outp)
{
    __shared__ __align__(16) unsigned char fsm[34816];
    const int bn = blockIdx.x, bo = blockIdx.y, b = blockIdx.z;
    const int tid = threadIdx.x;
    const int wave = tid >> 6, lane = tid & 63;
    const int quad = lane >> 4, l16 = lane & 15;
    const int wm = wave & 1, wn = wave >> 1;

    floatx4 acc[4][2] = {};

    for (int kc = 0; kc < 8; ++kc) {
        const bf16* __restrict__ actk = Act + ((size_t)b << 18) + (kc << 15);
        bf16x8 af[4], wf[2];
        #pragma unroll
        for (int p = 0; p < 4; ++p)
            af[p] = *(const bf16x8*)&actk[(bn * 128 + wm * 64 + p * 16 + l16) * 32 + quad * 8];
        #pragma unroll
        for (int p = 0; p < 2; ++p)
            wf[p] = *(const bf16x8*)&Wf[(((kc << 8) + bo * 64 + wn * 32 + p * 16 + l16) << 5) + quad * 8];
        #pragma unroll
        for (int i = 0; i < 4; ++i)
            #pragma unroll
            for (int j = 0; j < 2; ++j)
                acc[i][j] = __builtin_amdgcn_mfma_f32_16x16x32_bf16(af[i], wf[j], acc[i][j], 0, 0, 0);
    }

    const float sg = 1.0f / (1.0f + __expf(-gate[0]));

    float* rp = (float*)(fsm + wave * 8704);   // [oc 32][68]
    #pragma unroll
    for (int i = 0; i < 4; ++i)
        #pragma unroll
        for (int j = 0; j < 2; ++j) {
            const int oc = bo * 64 + wn * 32 + j * 16 + l16;
            const float bs = bias[oc];
            float4 o;
            o.x = acc[i][j][0] + bs; o.y = acc[i][j][1] + bs;
            o.z = acc[i][j][2] + bs; o.w = acc[i][j][3] + bs;
            *(float4*)&rp[(j * 16 + l16) * 68 + i * 16 + quad * 4] = o;
        }
    LGKM_WAIT();
    const int n0 = bn * 128 + wm * 64;
    #pragma unroll
    for (int it = 0; it < 8; ++it) {
        const int s = it * 64 + lane;
        const int ocl = s >> 4, nch = s & 15;
        const int oc = bo * 64 + wn * 32 + ocl;
        const int idx = ((b * 256 + oc) << 10) + n0 + nch * 4;
        float4 v = *(const float4*)&rp[ocl * 68 + nch * 4];
        const float4 cc = *(const float4*)&c2[idx];
        const float4 rr = *(const float4*)&resid[idx];
        float4 o;
        o.x = cc.x + sg * v.x + rr.x; o.y = cc.y + sg * v.y + rr.y;
        o.z = cc.z + sg * v.z + rr.z; o.w = cc.w + sg * v.w + rr.w;
        o.x = o.x < 0.0f ? 0.0f : o.x; o.y = o.y < 0.0f ? 0.0f : o.y;
        o.z = o.z < 0.0f ? 0.0f : o.z; o.w = o.w < 0.0f ? 0.0f : o.w;
        *(float4*)&outp[idx] = o;
    }
}

extern "C" void kernel_launch(void* const* d_in, const int* in_sizes, int n_in,
                              void* d_out, int out_size, void* d_ws, size_t ws_size,
                              hipStream_t stream)
{
    const float* x    = (const float*)d_in[0];
    const float* w1   = (const float*)d_in[1];
    const float* cb1  = (const float*)d_in[2];
    const float* g1   = (const float*)d_in[3];
    const float* be1  = (const float*)d_in[4];
    const float* mu1  = (const float*)d_in[5];
    const float* va1  = (const float*)d_in[6];
    const float* w2   = (const float*)d_in[7];
    const float* cb2  = (const float*)d_in[8];
    const float* g2   = (const float*)d_in[9];
    const float* be2  = (const float*)d_in[10];
    const float* mu2  = (const float*)d_in[11];
    const float* va2  = (const float*)d_in[12];
    const float* qw   = (const float*)d_in[13];
    const float* qb_  = (const float*)d_in[14];
    const float* kw   = (const float*)d_in[15];
    const float* kb_  = (const float*)d_in[16];
    const float* vw   = (const float*)d_in[17];
    const float* vb_  = (const float*)d_in[18];
    const float* ow   = (const float*)d_in[19];
    const float* ob_  = (const float*)d_in[20];
    const float* gate = (const float*)d_in[21];

    char* ws = (char*)d_ws;
    bf16*  xk    = (bf16*) (ws + 0);          //  8,388,608  k-blocked x
    bf16*  y1k   = (bf16*) (ws + 8388608);    //  8,388,608  conv1 out k-blocked
    bf16*  attnk = (bf16*) (ws + 8388608);    //  reuse (y1k dead after conv2)
    float* c2    = (float*)(ws + 16777216);   // 16,777,216  conv2 out c-major fp32
    bf16*  qT    = (bf16*) (ws + 33554432);   //  8,388,608  head-blocked
    bf16*  kT    = (bf16*) (ws + 41943040);   //  8,388,608  head-blocked
    bf16*  vbuf  = (bf16*) (ws + 50331648);   //  8,388,608  c-major
    bf16*  w1f   = (bf16*) (ws + 58720256);
    bf16*  w2f   = (bf16*) (ws + 59899904);
    bf16*  qwf   = (bf16*) (ws + 61079552);
    bf16*  kwf   = (bf16*) (ws + 61210624);
    bf16*  vwf   = (bf16*) (ws + 61341696);
    bf16*  owf   = (bf16*) (ws + 61472768);

    dim3 blk(256, 1, 1);
    prep_all<<<dim3(2432), blk, 0, stream>>>(x, w1, w2, qw, kw, vw, ow,
                                             xk, w1f, w2f, qwf, kwf, vwf, owf);

    // phase1: conv1 + qkv (independent, co-scheduled)
    phase1_k<<<dim3(2048), blk, 0, stream>>>(w1f, xk, cb1, g1, be1, mu1, va1, y1k,
                                             qwf, kwf, vwf, qb_, kb_, vb_,
                                             qT, kT, vbuf, 0.2550392430300696f);
    // phase2: conv2 + attention (independent, co-scheduled)
    phase2_k<<<dim3(1536), blk, 0, stream>>>(w2f, y1k, cb2, g2, be2, mu2, va2, c2,
                                             qT, kT, vbuf, attnk);
    // final projection + gate + residual + relu
    dim3 gg(8, 4, 16);
    fi_k<<<gg, blk, 0, stream>>>(owf, attnk, ob_, c2, x, gate, (float*)d_out);

    (void)in_sizes; (void)n_in; (void)out_size; (void)ws_size;
}

// Round 12
// 230.087 us; speedup vs baseline: 1.3506x; 1.0501x over previous
//
#include <hip/hip_runtime.h>
#include <hip/hip_bf16.h>

using bf16 = __hip_bfloat16;
typedef __attribute__((ext_vector_type(4))) float floatx4;
typedef __attribute__((ext_vector_type(8))) __bf16 bf16x8;
typedef __attribute__((ext_vector_type(4))) __bf16 bf16x4;

#define LGKM_WAIT() asm volatile("s_waitcnt lgkmcnt(0)" ::: "memory")

// ---------------------------------------------------------------------------
// Weight prep: fp32 [O=256][K=256][taps] -> bf16 frag-ordered
// [t][kc][o 0..255][kk 0..31]
// ---------------------------------------------------------------------------
__device__ __forceinline__ void prep_one(const float* __restrict__ src,
                                         bf16* __restrict__ dst, int idx, int ntaps)
{
    const int kk = idx & 31, o = (idx >> 5) & 255, kc = (idx >> 13) & 7, t = idx >> 16;
    dst[idx] = __float2bfloat16(src[(o * 256 + kc * 32 + kk) * ntaps + t]);
}

// prep_all: blocks 0..1023 x-transpose; 1024..1599 w1; 1600..1855 1x1 weights.
// (w2 prep moved into phase1 — only phase2 consumes it.)
__global__ __launch_bounds__(256) void prep_all(
    const float* __restrict__ x, const float* __restrict__ w1,
    const float* __restrict__ qw, const float* __restrict__ kw,
    const float* __restrict__ vw, const float* __restrict__ ow,
    bf16* __restrict__ xk, bf16* __restrict__ w1f,
    bf16* __restrict__ qwf, bf16* __restrict__ kwf,
    bf16* __restrict__ vwf, bf16* __restrict__ owf)
{
    __shared__ float T[64][65];
    const int blk = blockIdx.x, tid = threadIdx.x;
    if (blk < 1024) {
        const int n0 = (blk & 15) * 64, c0 = ((blk >> 4) & 3) * 64, b = blk >> 6;
        #pragma unroll
        for (int it = 0; it < 4; ++it) {
            const int tau = tid + it * 256;
            const int c = tau >> 4, seg = tau & 15;
            const float4 vv = *(const float4*)&x[((b * 256 + c0 + c) << 10) + n0 + seg * 4];
            T[seg * 4 + 0][c] = vv.x; T[seg * 4 + 1][c] = vv.y;
            T[seg * 4 + 2][c] = vv.z; T[seg * 4 + 3][c] = vv.w;
        }
        __syncthreads();
        #pragma unroll
        for (int it = 0; it < 2; ++it) {
            const int tau = tid + it * 256;
            const int n = tau >> 3, seg = tau & 7;
            bf16x8 o8;
            #pragma unroll
            for (int q = 0; q < 8; ++q) o8[q] = (__bf16)T[n][seg * 8 + q];
            const int c = c0 + seg * 8;
            *(bf16x8*)&xk[((((b << 3) + (c >> 5)) << 10) + n0 + n) * 32 + (c & 31)] = o8;
        }
    } else if (blk < 1600) {
        const int base = (blk - 1024) * 1024 + tid;
        #pragma unroll
        for (int k = 0; k < 4; ++k) prep_one(w1, w1f, base + k * 256, 9);
    } else {
        const int r = (blk - 1600) * 256 + tid;
        prep_one(qw, qwf, r, 1);
        prep_one(kw, kwf, r, 1);
        prep_one(vw, vwf, r, 1);
        prep_one(ow, owf, r, 1);
    }
}

// ---------------------------------------------------------------------------
// Conv3x3 GEMM body: double-buffered LDS halo tile (6x34, pad 40), one barrier
// per kc, act prefetch. 128sp x 64oc, waves 2x2, acc[4][2].
// MODE 0: BN+ReLU -> bf16 k-blocked | MODE 1: BN -> fp32 c-major (repacked)
// ---------------------------------------------------------------------------
template<int MODE>
__device__ __forceinline__ void conv_body(
    unsigned char* smb, int bn, int bo, int b,
    const bf16* __restrict__ Wf, const bf16* __restrict__ Act,
    const float* __restrict__ bias,
    const float* __restrict__ gam, const float* __restrict__ bet,
    const float* __restrict__ mu, const float* __restrict__ var,
    void* __restrict__ outp)
{
    const int tid = threadIdx.x;
    const int wave = tid >> 6, lane = tid & 63;
    const int quad = lane >> 4, l16 = lane & 15;
    const int wm = wave & 1, wn = wave >> 1;

    int srow[4], scol[4], sn[4]; bool sval[4];
    #pragma unroll
    for (int it = 0; it < 4; ++it) {
        const int s = tid + it * 256;
        const int row = s >> 2;
        const int yi = row / 34, x34 = row - yi * 34;
        const int gy = bn * 4 - 1 + yi, gx = x34 - 1;
        sval[it] = (s < 816) & (gy >= 0) & (gy < 32) & (gx >= 0) & (gx < 32);
        sn[it] = (gy << 5) + gx;
        srow[it] = row; scol[it] = (s & 3) * 8;
    }

    const bf16* __restrict__ act0 = Act + ((size_t)b << 18);
    bf16x8 rg[4];
    #pragma unroll
    for (int it = 0; it < 4; ++it) {
        bf16x8 v = {};
        if (sval[it]) v = *(const bf16x8*)&act0[sn[it] * 32 + scol[it]];
        rg[it] = v;
    }
    {
        bf16* st = (bf16*)smb;
        #pragma unroll
        for (int it = 0; it < 4; ++it)
            if (tid + it * 256 < 816) *(bf16x8*)&st[srow[it] * 40 + scol[it]] = rg[it];
    }
    __syncthreads();

    floatx4 acc[4][2] = {};

    for (int kc = 0; kc < 8; ++kc) {
        if (kc < 7) {
            const bf16* __restrict__ actn = act0 + ((kc + 1) << 15);
            #pragma unroll
            for (int it = 0; it < 4; ++it) {
                bf16x8 v = {};
                if (sval[it]) v = *(const bf16x8*)&actn[sn[it] * 32 + scol[it]];
                rg[it] = v;
            }
        }
        const bf16* __restrict__ cur = (const bf16*)(smb + (kc & 1) * 16320);
        #pragma unroll
        for (int t = 0; t < 9; ++t) {
            const int dy = t / 3 - 1, dx = t % 3 - 1;
            bf16x8 af[4], wf[2];
            #pragma unroll
            for (int p = 0; p < 4; ++p) {
                const int m = wm * 64 + p * 16 + l16;
                const int row = ((m >> 5) + 1 + dy) * 34 + ((m & 31) + 1 + dx);
                af[p] = *(const bf16x8*)&cur[row * 40 + quad * 8];
            }
            #pragma unroll
            for (int p = 0; p < 2; ++p)
                wf[p] = *(const bf16x8*)&Wf[((((t * 8 + kc) << 8) + bo * 64 + wn * 32 + p * 16 + l16) << 5) + quad * 8];
            #pragma unroll
            for (int i = 0; i < 4; ++i)
                #pragma unroll
                for (int j = 0; j < 2; ++j)
                    acc[i][j] = __builtin_amdgcn_mfma_f32_16x16x32_bf16(af[i], wf[j], acc[i][j], 0, 0, 0);
        }
        if (kc < 7) {
            bf16* nxt = (bf16*)(smb + ((kc + 1) & 1) * 16320);
            #pragma unroll
            for (int it = 0; it < 4; ++it)
                if (tid + it * 256 < 816) *(bf16x8*)&nxt[srow[it] * 40 + scol[it]] = rg[it];
        }
        __syncthreads();
    }

    if constexpr (MODE == 0) {
        bf16* rp = (bf16*)(smb + wave * 5120);   // [n 64][40]
        #pragma unroll
        for (int i = 0; i < 4; ++i)
            #pragma unroll
            for (int j = 0; j < 2; ++j) {
                const int oc = bo * 64 + wn * 32 + j * 16 + l16;
                const float inv = gam[oc] * rsqrtf(var[oc] + 1e-5f);
                const float sh = bet[oc] - mu[oc] * inv;
                const float bs = bias[oc];
                #pragma unroll
                for (int r = 0; r < 4; ++r) {
                    const float v = (acc[i][j][r] + bs) * inv + sh;
                    rp[(i * 16 + quad * 4 + r) * 40 + j * 16 + l16] =
                        __float2bfloat16(v < 0.0f ? 0.0f : v);
                }
            }
        LGKM_WAIT();
        const int kc2 = bo * 2 + wn;
        bf16* dst = (bf16*)outp + ((((size_t)b << 3) + kc2) << 15) + (bn * 128 + wm * 64) * 32;
        #pragma unroll
        for (int it = 0; it < 4; ++it) {
            const int s = it * 64 + lane;
            const int nl = s >> 2, cp = (s & 3) * 8;
            *(bf16x8*)&dst[nl * 32 + cp] = *(const bf16x8*)&rp[nl * 40 + cp];
        }
    } else {
        float* rp = (float*)(smb + wave * 8704);   // [oc 32][68]
        #pragma unroll
        for (int i = 0; i < 4; ++i)
            #pragma unroll
            for (int j = 0; j < 2; ++j) {
                const int oc = bo * 64 + wn * 32 + j * 16 + l16;
                const float inv = gam[oc] * rsqrtf(var[oc] + 1e-5f);
                const float sh = bet[oc] - mu[oc] * inv;
                const float bs = bias[oc];
                float4 o;
                o.x = (acc[i][j][0] + bs) * inv + sh;
                o.y = (acc[i][j][1] + bs) * inv + sh;
                o.z = (acc[i][j][2] + bs) * inv + sh;
                o.w = (acc[i][j][3] + bs) * inv + sh;
                *(float4*)&rp[(j * 16 + l16) * 68 + i * 16 + quad * 4] = o;
            }
        LGKM_WAIT();
        const int n0 = bn * 128 + wm * 64;
        #pragma unroll
        for (int it = 0; it < 8; ++it) {
            const int s = it * 64 + lane;
            const int ocl = s >> 4, nch = s & 15;
            const int oc = bo * 64 + wn * 32 + ocl;
            float4 v = *(const float4*)&rp[ocl * 68 + nch * 4];
            *(float4*)&((float*)outp)[((b * 256 + oc) << 10) + n0 + nch * 4] = v;
        }
    }
}

// ---------------------------------------------------------------------------
// q/k/v projection body. q,k -> head-blocked via per-wave LDS repack;
// v -> d-blocked [b][h][key>>5][d][key&31] via DIRECT coalesced b64 stores
// (lane pattern quad*16B + l16*64B = contiguous 4KB per (i,j)).
// ---------------------------------------------------------------------------
__device__ __forceinline__ void qkv_body(
    unsigned char* qsm, int bn, int by, int b,
    const bf16* __restrict__ Wq, const bf16* __restrict__ Wk, const bf16* __restrict__ Wv,
    const bf16* __restrict__ Act,
    const float* __restrict__ bq, const float* __restrict__ bk, const float* __restrict__ bv,
    bf16* __restrict__ Oq, bf16* __restrict__ Ok, bf16* __restrict__ Ov, float qscale)
{
    const int sel = by >> 2, bo = by & 3;
    const bf16* __restrict__ Wf = (sel == 0) ? Wq : (sel == 1) ? Wk : Wv;
    const float* __restrict__ bias = (sel == 0) ? bq : (sel == 1) ? bk : bv;
    const float scale = (sel == 0) ? qscale : 1.0f;

    const int tid = threadIdx.x;
    const int wave = tid >> 6, lane = tid & 63;
    const int quad = lane >> 4, l16 = lane & 15;
    const int wm = wave & 1, wn = wave >> 1;

    floatx4 acc[4][2] = {};

    for (int kc = 0; kc < 8; ++kc) {
        const bf16* __restrict__ actk = Act + ((size_t)b << 18) + (kc << 15);
        bf16x8 af[4], wf[2];
        #pragma unroll
        for (int p = 0; p < 4; ++p)
            af[p] = *(const bf16x8*)&actk[(bn * 128 + wm * 64 + p * 16 + l16) * 32 + quad * 8];
        #pragma unroll
        for (int p = 0; p < 2; ++p)
            wf[p] = *(const bf16x8*)&Wf[(((kc << 8) + bo * 64 + wn * 32 + p * 16 + l16) << 5) + quad * 8];
        #pragma unroll
        for (int i = 0; i < 4; ++i)
            #pragma unroll
            for (int j = 0; j < 2; ++j)
                acc[i][j] = __builtin_amdgcn_mfma_f32_16x16x32_bf16(af[i], wf[j], acc[i][j], 0, 0, 0);
    }

    if (sel < 2) {
        bf16* rp = (bf16*)(qsm + wave * 5120);   // [n 64][40]
        #pragma unroll
        for (int i = 0; i < 4; ++i)
            #pragma unroll
            for (int j = 0; j < 2; ++j) {
                const int oc = bo * 64 + wn * 32 + j * 16 + l16;
                const float bs = bias[oc];
                #pragma unroll
                for (int r = 0; r < 4; ++r)
                    rp[(i * 16 + quad * 4 + r) * 40 + j * 16 + l16] =
                        __float2bfloat16((acc[i][j][r] + bs) * scale);
            }
        LGKM_WAIT();
        bf16* __restrict__ outp = (sel == 0) ? Oq : Ok;
        const int h = bo * 2 + wn;
        bf16* dst = outp + ((((size_t)b << 3) + h) << 15) + (bn * 128 + wm * 64) * 32;
        #pragma unroll
        for (int it = 0; it < 4; ++it) {
            const int s = it * 64 + lane;
            const int nl = s >> 2, cp = (s & 3) * 8;
            *(bf16x8*)&dst[nl * 32 + cp] = *(const bf16x8*)&rp[nl * 40 + cp];
        }
    } else {
        // V d-blocked: [b][h][key>>5][d 0..31][key&31], direct b64 stores
        #pragma unroll
        for (int i = 0; i < 4; ++i)
            #pragma unroll
            for (int j = 0; j < 2; ++j) {
                const int oc = bo * 64 + wn * 32 + j * 16 + l16;
                const int h = oc >> 5, d = oc & 31;
                const float bs = bias[oc];
                bf16x4 o4;
                #pragma unroll
                for (int r = 0; r < 4; ++r) o4[r] = (__bf16)(acc[i][j][r] + bs);
                const int key = bn * 128 + wm * 64 + i * 16 + quad * 4;
                *(bf16x4*)&Ov[(((((size_t)b << 3) + h) * 32 + (key >> 5)) * 32 + d) * 32 + (key & 31)] = o4;
            }
    }
}

// ---------------------------------------------------------------------------
// Flash attention body: S^T = K Q^T, 32 q/wave; XCD swizzle h = L&7;
// exp2-domain softmax (q pre-scaled by log2e/sqrt(32)); V d-blocked so PV
// A-frags are coalesced 16x64B loads. Per-wave P in LDS, no barriers.
// ---------------------------------------------------------------------------
__device__ __forceinline__ void attn_body(
    unsigned char* smb, int L,
    const bf16* __restrict__ Q, const bf16* __restrict__ K,
    const bf16* __restrict__ V, bf16* __restrict__ O)
{
    bf16 (*Pl)[32][136] = (bf16 (*)[32][136])smb;   // [wave][q_local][key]

    const int h = L & 7, slot = L >> 3;
    const int b = slot & 15, qb = slot >> 4;
    const int tid = threadIdx.x;
    const int wave = tid >> 6, lane = tid & 63;
    const int quad = lane >> 4, l16 = lane & 15;

    const bf16* __restrict__ Qh = Q + ((((size_t)b << 3) + h) << 15);
    const bf16* __restrict__ Kh = K + ((((size_t)b << 3) + h) << 15);
    const bf16* __restrict__ Vh = V + ((((size_t)b << 3) + h) << 15);
    const int qrow0 = qb * 128 + wave * 32;

    bf16x8 qf[2];
    #pragma unroll
    for (int i = 0; i < 2; ++i)
        qf[i] = *(const bf16x8*)&Qh[(qrow0 + i * 16 + l16) * 32 + quad * 8];

    float lp[2] = {0.0f, 0.0f};
    floatx4 oacc[2][2] = {};

    for (int kt = 0; kt < 8; ++kt) {
        bf16x8 kf[8];
        #pragma unroll
        for (int kb = 0; kb < 8; ++kb)
            kf[kb] = *(const bf16x8*)&Kh[(kt * 128 + kb * 16 + l16) * 32 + quad * 8];
        // V d-blocked coalesced: row = ((kt*4+kk)*32 + d)
        bf16x8 vb[2][4];
        #pragma unroll
        for (int jd = 0; jd < 2; ++jd)
            #pragma unroll
            for (int kk = 0; kk < 4; ++kk)
                vb[jd][kk] = *(const bf16x8*)&Vh[(((kt * 4 + kk) << 5) + jd * 16 + l16) * 32 + quad * 8];

        #pragma unroll
        for (int kb = 0; kb < 8; ++kb) {
            #pragma unroll
            for (int i = 0; i < 2; ++i) {
                floatx4 zz = {0.f, 0.f, 0.f, 0.f};
                floatx4 st = __builtin_amdgcn_mfma_f32_16x16x32_bf16(kf[kb], qf[i], zz, 0, 0, 0);
                const float e0 = __builtin_amdgcn_exp2f(st[0]);
                const float e1 = __builtin_amdgcn_exp2f(st[1]);
                const float e2 = __builtin_amdgcn_exp2f(st[2]);
                const float e3 = __builtin_amdgcn_exp2f(st[3]);
                lp[i] += (e0 + e1) + (e2 + e3);
                bf16x4 p4 = {(__bf16)e0, (__bf16)e1, (__bf16)e2, (__bf16)e3};
                *(bf16x4*)&Pl[wave][i * 16 + l16][kb * 16 + quad * 4] = p4;
            }
        }

        #pragma unroll
        for (int kk = 0; kk < 4; ++kk) {
            bf16x8 pf[2];
            #pragma unroll
            for (int i = 0; i < 2; ++i)
                pf[i] = *(const bf16x8*)&Pl[wave][i * 16 + l16][kk * 32 + quad * 8];
            #pragma unroll
            for (int jd = 0; jd < 2; ++jd)
                #pragma unroll
                for (int i = 0; i < 2; ++i)
                    oacc[jd][i] = __builtin_amdgcn_mfma_f32_16x16x32_bf16(
                        vb[jd][kk], pf[i], oacc[jd][i], 0, 0, 0);
        }
    }

    bf16* __restrict__ Oh = O + ((((size_t)b << 3) + h) << 15);
    #pragma unroll
    for (int i = 0; i < 2; ++i) {
        float l = lp[i];
        l += __shfl_xor(l, 16, 64);
        l += __shfl_xor(l, 32, 64);
        const float inv = 1.0f / l;
        const int qn = qrow0 + i * 16 + l16;
        #pragma unroll
        for (int jd = 0; jd < 2; ++jd) {
            bf16x4 o4;
            #pragma unroll
            for (int r = 0; r < 4; ++r) o4[r] = (__bf16)(oacc[jd][i][r] * inv);
            *(bf16x4*)&Oh[qn * 32 + jd * 16 + quad * 4] = o4;
        }
    }
}

// ---------------------------------------------------------------------------
// phase1: conv1 (0..511) + qkv (512..2047) + w2 prep (2048..2623).
// ---------------------------------------------------------------------------
__global__ __launch_bounds__(256) void phase1_k(
    const bf16* __restrict__ w1f, const bf16* __restrict__ xk,
    const float* __restrict__ cb1,
    const float* __restrict__ g1, const float* __restrict__ be1,
    const float* __restrict__ mu1, const float* __restrict__ va1,
    bf16* __restrict__ y1k,
    const bf16* __restrict__ qwf, const bf16* __restrict__ kwf, const bf16* __restrict__ vwf,
    const float* __restrict__ qb_, const float* __restrict__ kb_, const float* __restrict__ vb_,
    bf16* __restrict__ qT, bf16* __restrict__ kT, bf16* __restrict__ vbuf, float qscale,
    const float* __restrict__ w2, bf16* __restrict__ w2f)
{
    __shared__ __align__(16) unsigned char smb[34816];
    const int L = blockIdx.x;
    if (L < 512) {
        const int bn = L & 7, bo = (L >> 3) & 3, b = L >> 5;
        conv_body<0>(smb, bn, bo, b, w1f, xk, cb1, g1, be1, mu1, va1, (void*)y1k);
    } else if (L < 2048) {
        const int L2 = L - 512;
        const int bn = L2 & 7, by = (L2 >> 3) % 12, b = L2 / 96;
        qkv_body(smb, bn, by, b, qwf, kwf, vwf, xk, qb_, kb_, vb_, qT, kT, vbuf, qscale);
    } else {
        const int base = (L - 2048) * 1024 + threadIdx.x;
        #pragma unroll
        for (int k = 0; k < 4; ++k) prep_one(w2, w2f, base + k * 256, 9);
    }
}

// ---------------------------------------------------------------------------
// phase2: conv2 (0..511) + attention (512..1535).
// ---------------------------------------------------------------------------
__global__ __launch_bounds__(256) void phase2_k(
    const bf16* __restrict__ w2f, const bf16* __restrict__ y1k,
    const float* __restrict__ cb2,
    const float* __restrict__ g2, const float* __restrict__ be2,
    const float* __restrict__ mu2, const float* __restrict__ va2,
    float* __restrict__ c2,
    const bf16* __restrict__ qT, const bf16* __restrict__ kT,
    const bf16* __restrict__ vbuf, bf16* __restrict__ attnk)
{
    __shared__ __align__(16) unsigned char smb[34816];
    const int L = blockIdx.x;
    if (L < 512) {
        const int bn = L & 7, bo = (L >> 3) & 3, b = L >> 5;
        conv_body<1>(smb, bn, bo, b, w2f, y1k, cb2, g2, be2, mu2, va2, (void*)c2);
    } else {
        attn_body(smb, L - 512, qT, kT, vbuf, attnk);
    }
}

// ---------------------------------------------------------------------------
// Final: out = relu(c2 + sigmoid(gate)*(ow@attn + ob) + x), fp32 c-major.
// ---------------------------------------------------------------------------
__global__ __launch_bounds__(256) void fi_k(
    const bf16* __restrict__ Wf, const bf16* __restrict__ Act,
    const float* __restrict__ bias,
    const float* __restrict__ c2, const float* __restrict__ resid,
    const float* __restrict__ gate, float* __restrict__ outp)
{
    __shared__ __align__(16) unsigned char fsm[34816];
    const int bn = blockIdx.x, bo = blockIdx.y, b = blockIdx.z;
    const int tid = threadIdx.x;
    const int wave = tid >> 6, lane = tid & 63;
    const int quad = lane >> 4, l16 = lane & 15;
    const int wm = wave & 1, wn = wave >> 1;

    floatx4 acc[4][2] = {};

    for (int kc = 0; kc < 8; ++kc) {
        const bf16* __restrict__ actk = Act + ((size_t)b << 18) + (kc << 15);
        bf16x8 af[4], wf[2];
        #pragma unroll
        for (int p = 0; p < 4; ++p)
            af[p] = *(const bf16x8*)&actk[(bn * 128 + wm * 64 + p * 16 + l16) * 32 + quad * 8];
        #pragma unroll
        for (int p = 0; p < 2; ++p)
            wf[p] = *(const bf16x8*)&Wf[(((kc << 8) + bo * 64 + wn * 32 + p * 16 + l16) << 5) + quad * 8];
        #pragma unroll
        for (int i = 0; i < 4; ++i)
            #pragma unroll
            for (int j = 0; j < 2; ++j)
                acc[i][j] = __builtin_amdgcn_mfma_f32_16x16x32_bf16(af[i], wf[j], acc[i][j], 0, 0, 0);
    }

    const float sg = 1.0f / (1.0f + __expf(-gate[0]));

    float* rp = (float*)(fsm + wave * 8704);   // [oc 32][68]
    #pragma unroll
    for (int i = 0; i < 4; ++i)
        #pragma unroll
        for (int j = 0; j < 2; ++j) {
            const int oc = bo * 64 + wn * 32 + j * 16 + l16;
            const float bs = bias[oc];
            float4 o;
            o.x = acc[i][j][0] + bs; o.y = acc[i][j][1] + bs;
            o.z = acc[i][j][2] + bs; o.w = acc[i][j][3] + bs;
            *(float4*)&rp[(j * 16 + l16) * 68 + i * 16 + quad * 4] = o;
        }
    LGKM_WAIT();
    const int n0 = bn * 128 + wm * 64;
    #pragma unroll
    for (int it = 0; it < 8; ++it) {
        const int s = it * 64 + lane;
        const int ocl = s >> 4, nch = s & 15;
        const int oc = bo * 64 + wn * 32 + ocl;
        const int idx = ((b * 256 + oc) << 10) + n0 + nch * 4;
        float4 v = *(const float4*)&rp[ocl * 68 + nch * 4];
        const float4 cc = *(const float4*)&c2[idx];
        const float4 rr = *(const float4*)&resid[idx];
        float4 o;
        o.x = cc.x + sg * v.x + rr.x; o.y = cc.y + sg * v.y + rr.y;
        o.z = cc.z + sg * v.z + rr.z; o.w = cc.w + sg * v.w + rr.w;
        o.x = o.x < 0.0f ? 0.0f : o.x; o.y = o.y < 0.0f ? 0.0f : o.y;
        o.z = o.z < 0.0f ? 0.0f : o.z; o.w = o.w < 0.0f ? 0.0f : o.w;
        *(float4*)&outp[idx] = o;
    }
}

extern "C" void kernel_launch(void* const* d_in, const int* in_sizes, int n_in,
                              void* d_out, int out_size, void* d_ws, size_t ws_size,
                              hipStream_t stream)
{
    const float* x    = (const float*)d_in[0];
    const float* w1   = (const float*)d_in[1];
    const float* cb1  = (const float*)d_in[2];
    const float* g1   = (const float*)d_in[3];
    const float* be1  = (const float*)d_in[4];
    const float* mu1  = (const float*)d_in[5];
    const float* va1  = (const float*)d_in[6];
    const float* w2   = (const float*)d_in[7];
    const float* cb2  = (const float*)d_in[8];
    const float* g2   = (const float*)d_in[9];
    const float* be2  = (const float*)d_in[10];
    const float* mu2  = (const float*)d_in[11];
    const float* va2  = (const float*)d_in[12];
    const float* qw   = (const float*)d_in[13];
    const float* qb_  = (const float*)d_in[14];
    const float* kw   = (const float*)d_in[15];
    const float* kb_  = (const float*)d_in[16];
    const float* vw   = (const float*)d_in[17];
    const float* vb_  = (const float*)d_in[18];
    const float* ow   = (const float*)d_in[19];
    const float* ob_  = (const float*)d_in[20];
    const float* gate = (const float*)d_in[21];

    char* ws = (char*)d_ws;
    bf16*  xk    = (bf16*) (ws + 0);          //  8,388,608  k-blocked x
    bf16*  y1k   = (bf16*) (ws + 8388608);    //  8,388,608  conv1 out k-blocked
    bf16*  attnk = (bf16*) (ws + 8388608);    //  reuse (y1k dead after conv2)
    float* c2    = (float*)(ws + 16777216);   // 16,777,216  conv2 out c-major fp32
    bf16*  qT    = (bf16*) (ws + 33554432);   //  8,388,608  head-blocked
    bf16*  kT    = (bf16*) (ws + 41943040);   //  8,388,608  head-blocked
    bf16*  vbuf  = (bf16*) (ws + 50331648);   //  8,388,608  d-blocked
    bf16*  w1f   = (bf16*) (ws + 58720256);
    bf16*  w2f   = (bf16*) (ws + 59899904);
    bf16*  qwf   = (bf16*) (ws + 61079552);
    bf16*  kwf   = (bf16*) (ws + 61210624);
    bf16*  vwf   = (bf16*) (ws + 61341696);
    bf16*  owf   = (bf16*) (ws + 61472768);

    dim3 blk(256, 1, 1);
    prep_all<<<dim3(1856), blk, 0, stream>>>(x, w1, qw, kw, vw, ow,
                                             xk, w1f, qwf, kwf, vwf, owf);

    // phase1: conv1 + qkv + w2-prep (independent, co-scheduled)
    phase1_k<<<dim3(2624), blk, 0, stream>>>(w1f, xk, cb1, g1, be1, mu1, va1, y1k,
                                             qwf, kwf, vwf, qb_, kb_, vb_,
                                             qT, kT, vbuf, 0.2550392430300696f,
                                             w2, w2f);
    // phase2: conv2 + attention (independent, co-scheduled)
    phase2_k<<<dim3(1536), blk, 0, stream>>>(w2f, y1k, cb2, g2, be2, mu2, va2, c2,
                                             qT, kT, vbuf, attnk);
    // final projection + gate + residual + relu
    dim3 gg(8, 4, 16);
    fi_k<<<gg, blk, 0, stream>>>(owf, attnk, ob_, c2, x, gate, (float*)d_out);

    (void)in_sizes; (void)n_in; (void)out_size; (void)ws_size;
}

// Round 13
// 228.847 us; speedup vs baseline: 1.3580x; 1.0054x over previous
//
#include <hip/hip_runtime.h>
#include <hip/hip_bf16.h>

using bf16 = __hip_bfloat16;
typedef __attribute__((ext_vector_type(4))) float floatx4;
typedef __attribute__((ext_vector_type(16))) float floatx16;
typedef __attribute__((ext_vector_type(8))) __bf16 bf16x8;
typedef __attribute__((ext_vector_type(4))) __bf16 bf16x4;

#define LGKM_WAIT() asm volatile("s_waitcnt lgkmcnt(0)" ::: "memory")

// XCD-aware remap: 1024 = 16bn x 4bo x 16b, xcd = L&7 owns a b-pair.
__device__ __forceinline__ void remap1024(int L, int& bn, int& bo, int& b)
{
    const int xcd = L & 7, slot = L >> 3;
    b  = (xcd << 1) | (slot & 1);
    bo = (slot >> 1) & 3;
    bn = slot >> 3;
}

// ---------------------------------------------------------------------------
// Weight prep: fp32 [O=256][K=256][taps] -> bf16 frag-ordered
// [t][kc][o 0..255][kk 0..31]
// ---------------------------------------------------------------------------
__device__ __forceinline__ void prep_one(const float* __restrict__ src,
                                         bf16* __restrict__ dst, int idx, int ntaps)
{
    const int kk = idx & 31, o = (idx >> 5) & 255, kc = (idx >> 13) & 7, t = idx >> 16;
    dst[idx] = __float2bfloat16(src[(o * 256 + kc * 32 + kk) * ntaps + t]);
}

// prep_all: 0..1023 x-transpose; 1024..1599 w1; 1600..1855 1x1 weights.
__global__ __launch_bounds__(256) void prep_all(
    const float* __restrict__ x, const float* __restrict__ w1,
    const float* __restrict__ qw, const float* __restrict__ kw,
    const float* __restrict__ vw, const float* __restrict__ ow,
    bf16* __restrict__ xk, bf16* __restrict__ w1f,
    bf16* __restrict__ qwf, bf16* __restrict__ kwf,
    bf16* __restrict__ vwf, bf16* __restrict__ owf)
{
    __shared__ float T[64][65];
    const int blk = blockIdx.x, tid = threadIdx.x;
    if (blk < 1024) {
        const int n0 = (blk & 15) * 64, c0 = ((blk >> 4) & 3) * 64, b = blk >> 6;
        #pragma unroll
        for (int it = 0; it < 4; ++it) {
            const int tau = tid + it * 256;
            const int c = tau >> 4, seg = tau & 15;
            const float4 vv = *(const float4*)&x[((b * 256 + c0 + c) << 10) + n0 + seg * 4];
            T[seg * 4 + 0][c] = vv.x; T[seg * 4 + 1][c] = vv.y;
            T[seg * 4 + 2][c] = vv.z; T[seg * 4 + 3][c] = vv.w;
        }
        __syncthreads();
        #pragma unroll
        for (int it = 0; it < 2; ++it) {
            const int tau = tid + it * 256;
            const int n = tau >> 3, seg = tau & 7;
            bf16x8 o8;
            #pragma unroll
            for (int q = 0; q < 8; ++q) o8[q] = (__bf16)T[n][seg * 8 + q];
            const int c = c0 + seg * 8;
            *(bf16x8*)&xk[((((b << 3) + (c >> 5)) << 10) + n0 + n) * 32 + (c & 31)] = o8;
        }
    } else if (blk < 1600) {
        const int base = (blk - 1024) * 1024 + tid;
        #pragma unroll
        for (int k = 0; k < 4; ++k) prep_one(w1, w1f, base + k * 256, 9);
    } else {
        const int r = (blk - 1600) * 256 + tid;
        prep_one(qw, qwf, r, 1);
        prep_one(kw, kwf, r, 1);
        prep_one(vw, vwf, r, 1);
        prep_one(ow, owf, r, 1);
    }
}

// ---------------------------------------------------------------------------
// Conv3x3 GEMM body: double-buffered LDS halo tile (6x34, pad 40), one barrier
// per kc, act prefetch. 128sp x 64oc, waves 2x2, acc[4][2].
// MODE 0: BN+ReLU -> bf16 k-blocked | MODE 1: BN -> bf16 c-major (repacked)
// ---------------------------------------------------------------------------
template<int MODE>
__device__ __forceinline__ void conv_body(
    unsigned char* smb, int bn, int bo, int b,
    const bf16* __restrict__ Wf, const bf16* __restrict__ Act,
    const float* __restrict__ bias,
    const float* __restrict__ gam, const float* __restrict__ bet,
    const float* __restrict__ mu, const float* __restrict__ var,
    bf16* __restrict__ outp)
{
    const int tid = threadIdx.x;
    const int wave = tid >> 6, lane = tid & 63;
    const int quad = lane >> 4, l16 = lane & 15;
    const int wm = wave & 1, wn = wave >> 1;

    int srow[4], scol[4], sn[4]; bool sval[4];
    #pragma unroll
    for (int it = 0; it < 4; ++it) {
        const int s = tid + it * 256;
        const int row = s >> 2;
        const int yi = row / 34, x34 = row - yi * 34;
        const int gy = bn * 4 - 1 + yi, gx = x34 - 1;
        sval[it] = (s < 816) & (gy >= 0) & (gy < 32) & (gx >= 0) & (gx < 32);
        sn[it] = (gy << 5) + gx;
        srow[it] = row; scol[it] = (s & 3) * 8;
    }

    const bf16* __restrict__ act0 = Act + ((size_t)b << 18);
    bf16x8 rg[4];
    #pragma unroll
    for (int it = 0; it < 4; ++it) {
        bf16x8 v = {};
        if (sval[it]) v = *(const bf16x8*)&act0[sn[it] * 32 + scol[it]];
        rg[it] = v;
    }
    {
        bf16* st = (bf16*)smb;
        #pragma unroll
        for (int it = 0; it < 4; ++it)
            if (tid + it * 256 < 816) *(bf16x8*)&st[srow[it] * 40 + scol[it]] = rg[it];
    }
    __syncthreads();

    floatx4 acc[4][2] = {};

    for (int kc = 0; kc < 8; ++kc) {
        if (kc < 7) {
            const bf16* __restrict__ actn = act0 + ((kc + 1) << 15);
            #pragma unroll
            for (int it = 0; it < 4; ++it) {
                bf16x8 v = {};
                if (sval[it]) v = *(const bf16x8*)&actn[sn[it] * 32 + scol[it]];
                rg[it] = v;
            }
        }
        const bf16* __restrict__ cur = (const bf16*)(smb + (kc & 1) * 16320);
        #pragma unroll
        for (int t = 0; t < 9; ++t) {
            const int dy = t / 3 - 1, dx = t % 3 - 1;
            bf16x8 af[4], wf[2];
            #pragma unroll
            for (int p = 0; p < 4; ++p) {
                const int m = wm * 64 + p * 16 + l16;
                const int row = ((m >> 5) + 1 + dy) * 34 + ((m & 31) + 1 + dx);
                af[p] = *(const bf16x8*)&cur[row * 40 + quad * 8];
            }
            #pragma unroll
            for (int p = 0; p < 2; ++p)
                wf[p] = *(const bf16x8*)&Wf[((((t * 8 + kc) << 8) + bo * 64 + wn * 32 + p * 16 + l16) << 5) + quad * 8];
            #pragma unroll
            for (int i = 0; i < 4; ++i)
                #pragma unroll
                for (int j = 0; j < 2; ++j)
                    acc[i][j] = __builtin_amdgcn_mfma_f32_16x16x32_bf16(af[i], wf[j], acc[i][j], 0, 0, 0);
        }
        if (kc < 7) {
            bf16* nxt = (bf16*)(smb + ((kc + 1) & 1) * 16320);
            #pragma unroll
            for (int it = 0; it < 4; ++it)
                if (tid + it * 256 < 816) *(bf16x8*)&nxt[srow[it] * 40 + scol[it]] = rg[it];
        }
        __syncthreads();
    }

    if constexpr (MODE == 0) {
        // bf16 k-blocked out [b][oc>>5][n][oc&31]; per-wave repack [n 64][40]
        bf16* rp = (bf16*)(smb + wave * 5120);
        #pragma unroll
        for (int i = 0; i < 4; ++i)
            #pragma unroll
            for (int j = 0; j < 2; ++j) {
                const int oc = bo * 64 + wn * 32 + j * 16 + l16;
                const float inv = gam[oc] * rsqrtf(var[oc] + 1e-5f);
                const float sh = bet[oc] - mu[oc] * inv;
                const float bs = bias[oc];
                #pragma unroll
                for (int r = 0; r < 4; ++r) {
                    const float v = (acc[i][j][r] + bs) * inv + sh;
                    rp[(i * 16 + quad * 4 + r) * 40 + j * 16 + l16] =
                        __float2bfloat16(v < 0.0f ? 0.0f : v);
                }
            }
        LGKM_WAIT();
        const int kc2 = bo * 2 + wn;
        bf16* dst = outp + ((((size_t)b << 3) + kc2) << 15) + (bn * 128 + wm * 64) * 32;
        #pragma unroll
        for (int it = 0; it < 4; ++it) {
            const int s = it * 64 + lane;
            const int nl = s >> 2, cp = (s & 3) * 8;
            *(bf16x8*)&dst[nl * 32 + cp] = *(const bf16x8*)&rp[nl * 40 + cp];
        }
    } else {
        // bf16 c-major out; per-wave repack [oc 32][72]
        bf16* rp = (bf16*)(smb + wave * 4608);
        #pragma unroll
        for (int i = 0; i < 4; ++i)
            #pragma unroll
            for (int j = 0; j < 2; ++j) {
                const int oc = bo * 64 + wn * 32 + j * 16 + l16;
                const float inv = gam[oc] * rsqrtf(var[oc] + 1e-5f);
                const float sh = bet[oc] - mu[oc] * inv;
                const float bs = bias[oc];
                bf16x4 o4;
                #pragma unroll
                for (int r = 0; r < 4; ++r)
                    o4[r] = (__bf16)((acc[i][j][r] + bs) * inv + sh);
                *(bf16x4*)&rp[(j * 16 + l16) * 72 + i * 16 + quad * 4] = o4;
            }
        LGKM_WAIT();
        const int n0 = bn * 128 + wm * 64;
        #pragma unroll
        for (int it = 0; it < 4; ++it) {
            const int s = it * 64 + lane;
            const int ocl = s >> 3, nch = s & 7;
            const int oc = bo * 64 + wn * 32 + ocl;
            *(bf16x8*)&outp[((b * 256 + oc) << 10) + n0 + nch * 8] =
                *(const bf16x8*)&rp[ocl * 72 + nch * 8];
        }
    }
}

// ---------------------------------------------------------------------------
// q/k/v projection body. q,k -> head-blocked (per-wave LDS repack);
// v -> d-blocked [b][h][key>>5][d][key&31] via direct coalesced b64 stores.
// ---------------------------------------------------------------------------
__device__ __forceinline__ void qkv_body(
    unsigned char* qsm, int bn, int by, int b,
    const bf16* __restrict__ Wq, const bf16* __restrict__ Wk, const bf16* __restrict__ Wv,
    const bf16* __restrict__ Act,
    const float* __restrict__ bq, const float* __restrict__ bk, const float* __restrict__ bv,
    bf16* __restrict__ Oq, bf16* __restrict__ Ok, bf16* __restrict__ Ov, float qscale)
{
    const int sel = by >> 2, bo = by & 3;
    const bf16* __restrict__ Wf = (sel == 0) ? Wq : (sel == 1) ? Wk : Wv;
    const float* __restrict__ bias = (sel == 0) ? bq : (sel == 1) ? bk : bv;
    const float scale = (sel == 0) ? qscale : 1.0f;

    const int tid = threadIdx.x;
    const int wave = tid >> 6, lane = tid & 63;
    const int quad = lane >> 4, l16 = lane & 15;
    const int wm = wave & 1, wn = wave >> 1;

    floatx4 acc[4][2] = {};

    for (int kc = 0; kc < 8; ++kc) {
        const bf16* __restrict__ actk = Act + ((size_t)b << 18) + (kc << 15);
        bf16x8 af[4], wf[2];
        #pragma unroll
        for (int p = 0; p < 4; ++p)
            af[p] = *(const bf16x8*)&actk[(bn * 128 + wm * 64 + p * 16 + l16) * 32 + quad * 8];
        #pragma unroll
        for (int p = 0; p < 2; ++p)
            wf[p] = *(const bf16x8*)&Wf[(((kc << 8) + bo * 64 + wn * 32 + p * 16 + l16) << 5) + quad * 8];
        #pragma unroll
        for (int i = 0; i < 4; ++i)
            #pragma unroll
            for (int j = 0; j < 2; ++j)
                acc[i][j] = __builtin_amdgcn_mfma_f32_16x16x32_bf16(af[i], wf[j], acc[i][j], 0, 0, 0);
    }

    if (sel < 2) {
        bf16* rp = (bf16*)(qsm + wave * 5120);   // [n 64][40]
        #pragma unroll
        for (int i = 0; i < 4; ++i)
            #pragma unroll
            for (int j = 0; j < 2; ++j) {
                const int oc = bo * 64 + wn * 32 + j * 16 + l16;
                const float bs = bias[oc];
                #pragma unroll
                for (int r = 0; r < 4; ++r)
                    rp[(i * 16 + quad * 4 + r) * 40 + j * 16 + l16] =
                        __float2bfloat16((acc[i][j][r] + bs) * scale);
            }
        LGKM_WAIT();
        bf16* __restrict__ outp = (sel == 0) ? Oq : Ok;
        const int h = bo * 2 + wn;
        bf16* dst = outp + ((((size_t)b << 3) + h) << 15) + (bn * 128 + wm * 64) * 32;
        #pragma unroll
        for (int it = 0; it < 4; ++it) {
            const int s = it * 64 + lane;
            const int nl = s >> 2, cp = (s & 3) * 8;
            *(bf16x8*)&dst[nl * 32 + cp] = *(const bf16x8*)&rp[nl * 40 + cp];
        }
    } else {
        // V d-blocked: [b][h][key>>5][d][key&31]
        #pragma unroll
        for (int i = 0; i < 4; ++i)
            #pragma unroll
            for (int j = 0; j < 2; ++j) {
                const int oc = bo * 64 + wn * 32 + j * 16 + l16;
                const int h = oc >> 5, d = oc & 31;
                const float bs = bias[oc];
                bf16x4 o4;
                #pragma unroll
                for (int r = 0; r < 4; ++r) o4[r] = (__bf16)(acc[i][j][r] + bs);
                const int key = bn * 128 + wm * 64 + i * 16 + quad * 4;
                *(bf16x4*)&Ov[(((((size_t)b << 3) + h) * 32 + (key >> 5)) * 32 + d) * 32 + (key & 31)] = o4;
            }
    }
}

// ---------------------------------------------------------------------------
// Flash attention body, 32x32x16 MFMA: S^T = K Q^T (4 key-tiles, 2 chained
// k-steps each), PV = one 32d x 32q acc over 8 chained k-steps. 32 q/wave.
// XCD swizzle h=L&7; exp2-domain softmax; V d-blocked; per-wave P in LDS;
// no barriers. 32x32 C/D: row=(rg&3)+8*(rg>>2)+4*(lane>>5), col=lane&31.
// ---------------------------------------------------------------------------
__device__ __forceinline__ void attn_body(
    unsigned char* smb, int L,
    const bf16* __restrict__ Q, const bf16* __restrict__ K,
    const bf16* __restrict__ V, bf16* __restrict__ O)
{
    bf16 (*Pl)[32][136] = (bf16 (*)[32][136])smb;   // [wave][q_local][key]

    const int h = L & 7, slot = L >> 3;
    const int b = slot & 15, qb = slot >> 4;
    const int tid = threadIdx.x;
    const int wave = tid >> 6, lane = tid & 63;
    const int l31 = lane & 31, lh = lane >> 5;

    const bf16* __restrict__ Qh = Q + ((((size_t)b << 3) + h) << 15);
    const bf16* __restrict__ Kh = K + ((((size_t)b << 3) + h) << 15);
    const bf16* __restrict__ Vh = V + ((((size_t)b << 3) + h) << 15);
    const int qrow0 = qb * 128 + wave * 32;

    // Q B-frags: B[k=d][n=q], lane: n=l31, k=ks*16+lh*8+j
    bf16x8 qf[2];
    #pragma unroll
    for (int ks = 0; ks < 2; ++ks)
        qf[ks] = *(const bf16x8*)&Qh[(qrow0 + l31) * 32 + ks * 16 + lh * 8];

    float lp = 0.0f;
    floatx16 oacc = {};

    for (int kt = 0; kt < 8; ++kt) {
        // V A-frags (prefetch): A[m=d=l31][k=key], key = ks*16+lh*8+j
        bf16x8 vf[8];
        #pragma unroll
        for (int ks = 0; ks < 8; ++ks)
            vf[ks] = *(const bf16x8*)&Vh[((((kt << 2) + (ks >> 1)) << 5) + l31) * 32
                                         + (ks & 1) * 16 + lh * 8];

        // S^T per 32-key tile: D[key][q]
        #pragma unroll
        for (int kb = 0; kb < 4; ++kb) {
            bf16x8 ka0 = *(const bf16x8*)&Kh[(kt * 128 + kb * 32 + l31) * 32 + lh * 8];
            bf16x8 ka1 = *(const bf16x8*)&Kh[(kt * 128 + kb * 32 + l31) * 32 + 16 + lh * 8];
            floatx16 st = {};
            st = __builtin_amdgcn_mfma_f32_32x32x16_bf16(ka0, qf[0], st, 0, 0, 0);
            st = __builtin_amdgcn_mfma_f32_32x32x16_bf16(ka1, qf[1], st, 0, 0, 0);
            #pragma unroll
            for (int g = 0; g < 4; ++g) {
                const float e0 = __builtin_amdgcn_exp2f(st[g * 4 + 0]);
                const float e1 = __builtin_amdgcn_exp2f(st[g * 4 + 1]);
                const float e2 = __builtin_amdgcn_exp2f(st[g * 4 + 2]);
                const float e3 = __builtin_amdgcn_exp2f(st[g * 4 + 3]);
                lp += (e0 + e1) + (e2 + e3);
                bf16x4 p4 = {(__bf16)e0, (__bf16)e1, (__bf16)e2, (__bf16)e3};
                *(bf16x4*)&Pl[wave][l31][kb * 32 + g * 8 + lh * 4] = p4;
            }
        }

        // O += V P : B[k=key][n=q] = Pl[q=l31][key]
        #pragma unroll
        for (int ks = 0; ks < 8; ++ks) {
            bf16x8 pf = *(const bf16x8*)&Pl[wave][l31][ks * 16 + lh * 8];
            oacc = __builtin_amdgcn_mfma_f32_32x32x16_bf16(vf[ks], pf, oacc, 0, 0, 0);
        }
    }

    lp += __shfl_xor(lp, 32, 64);
    const float inv = 1.0f / lp;
    bf16* __restrict__ Oh = O + ((((size_t)b << 3) + h) << 15);
    #pragma unroll
    for (int g = 0; g < 4; ++g) {
        bf16x4 o4;
        #pragma unroll
        for (int r = 0; r < 4; ++r) o4[r] = (__bf16)(oacc[g * 4 + r] * inv);
        *(bf16x4*)&Oh[(qrow0 + l31) * 32 + g * 8 + lh * 4] = o4;
    }
}

// ---------------------------------------------------------------------------
// phase1: conv1 (0..511) + qkv (512..2047) + w2 prep (2048..2623).
// ---------------------------------------------------------------------------
__global__ __launch_bounds__(256) void phase1_k(
    const bf16* __restrict__ w1f, const bf16* __restrict__ xk,
    const float* __restrict__ cb1,
    const float* __restrict__ g1, const float* __restrict__ be1,
    const float* __restrict__ mu1, const float* __restrict__ va1,
    bf16* __restrict__ y1k,
    const bf16* __restrict__ qwf, const bf16* __restrict__ kwf, const bf16* __restrict__ vwf,
    const float* __restrict__ qb_, const float* __restrict__ kb_, const float* __restrict__ vb_,
    bf16* __restrict__ qT, bf16* __restrict__ kT, bf16* __restrict__ vbuf, float qscale,
    const float* __restrict__ w2, bf16* __restrict__ w2f)
{
    __shared__ __align__(16) unsigned char smb[34816];
    const int L = blockIdx.x;
    if (L < 512) {
        const int bn = L & 7, bo = (L >> 3) & 3, b = L >> 5;
        conv_body<0>(smb, bn, bo, b, w1f, xk, cb1, g1, be1, mu1, va1, y1k);
    } else if (L < 2048) {
        const int L2 = L - 512;
        const int bn = L2 & 7, by = (L2 >> 3) % 12, b = L2 / 96;
        qkv_body(smb, bn, by, b, qwf, kwf, vwf, xk, qb_, kb_, vb_, qT, kT, vbuf, qscale);
    } else {
        const int base = (L - 2048) * 1024 + threadIdx.x;
        #pragma unroll
        for (int k = 0; k < 4; ++k) prep_one(w2, w2f, base + k * 256, 9);
    }
}

// ---------------------------------------------------------------------------
// phase2: conv2 (0..511) + attention (512..1535). No aliasing: attnk is a
// dedicated buffer (r11/r12 aliased y1k — latent race, fixed).
// ---------------------------------------------------------------------------
__global__ __launch_bounds__(256) void phase2_k(
    const bf16* __restrict__ w2f, const bf16* __restrict__ y1k,
    const float* __restrict__ cb2,
    const float* __restrict__ g2, const float* __restrict__ be2,
    const float* __restrict__ mu2, const float* __restrict__ va2,
    bf16* __restrict__ c2b,
    const bf16* __restrict__ qT, const bf16* __restrict__ kT,
    const bf16* __restrict__ vbuf, bf16* __restrict__ attnk)
{
    __shared__ __align__(16) unsigned char smb[34816];
    const int L = blockIdx.x;
    if (L < 512) {
        const int bn = L & 7, bo = (L >> 3) & 3, b = L >> 5;
        conv_body<1>(smb, bn, bo, b, w2f, y1k, cb2, g2, be2, mu2, va2, c2b);
    } else {
        attn_body(smb, L - 512, qT, kT, vbuf, attnk);
    }
}

// ---------------------------------------------------------------------------
// Final: out = relu(c2 + sigmoid(gate)*(ow@attn + ob) + x), fp32 c-major.
// 64sp x 64oc, 1024 blocks (4/CU), XCD-remapped; per-wave repack epilogue;
// c2 read as bf16.
// ---------------------------------------------------------------------------
__global__ __launch_bounds__(256) void fi_k(
    const bf16* __restrict__ Wf, const bf16* __restrict__ Act,
    const float* __restrict__ bias,
    const bf16* __restrict__ c2b, const float* __restrict__ resid,
    const float* __restrict__ gate, float* __restrict__ outp)
{
    __shared__ __align__(16) unsigned char fsm[18432];
    int bn, bo, b; remap1024(blockIdx.x, bn, bo, b);
    const int tid = threadIdx.x;
    const int wave = tid >> 6, lane = tid & 63;
    const int quad = lane >> 4, l16 = lane & 15;
    const int wm = wave & 1, wn = wave >> 1;

    floatx4 acc[2][2] = {};

    for (int kc = 0; kc < 8; ++kc) {
        const bf16* __restrict__ actk = Act + ((size_t)b << 18) + (kc << 15);
        bf16x8 af[2], wf[2];
        #pragma unroll
        for (int p = 0; p < 2; ++p)
            af[p] = *(const bf16x8*)&actk[(bn * 64 + wm * 32 + p * 16 + l16) * 32 + quad * 8];
        #pragma unroll
        for (int p = 0; p < 2; ++p)
            wf[p] = *(const bf16x8*)&Wf[(((kc << 8) + bo * 64 + wn * 32 + p * 16 + l16) << 5) + quad * 8];
        #pragma unroll
        for (int i = 0; i < 2; ++i)
            #pragma unroll
            for (int j = 0; j < 2; ++j)
                acc[i][j] = __builtin_amdgcn_mfma_f32_16x16x32_bf16(af[i], wf[j], acc[i][j], 0, 0, 0);
    }

    const float sg = 1.0f / (1.0f + __expf(-gate[0]));

    float* rp = (float*)(fsm + wave * 4608);   // [oc 32][36]
    #pragma unroll
    for (int i = 0; i < 2; ++i)
        #pragma unroll
        for (int j = 0; j < 2; ++j) {
            const int oc = bo * 64 + wn * 32 + j * 16 + l16;
            const float bs = bias[oc];
            float4 o;
            o.x = acc[i][j][0] + bs; o.y = acc[i][j][1] + bs;
            o.z = acc[i][j][2] + bs; o.w = acc[i][j][3] + bs;
            *(float4*)&rp[(j * 16 + l16) * 36 + i * 16 + quad * 4] = o;
        }
    LGKM_WAIT();
    const int n0 = bn * 64 + wm * 32;
    #pragma unroll
    for (int it = 0; it < 4; ++it) {
        const int s = it * 64 + lane;
        const int ocl = s >> 3, nch = s & 7;
        const int oc = bo * 64 + wn * 32 + ocl;
        const int idx = ((b * 256 + oc) << 10) + n0 + nch * 4;
        float4 v = *(const float4*)&rp[ocl * 36 + nch * 4];
        const bf16x4 ccb = *(const bf16x4*)&c2b[idx];
        const float4 rr = *(const float4*)&resid[idx];
        float4 o;
        o.x = (float)ccb[0] + sg * v.x + rr.x;
        o.y = (float)ccb[1] + sg * v.y + rr.y;
        o.z = (float)ccb[2] + sg * v.z + rr.z;
        o.w = (float)ccb[3] + sg * v.w + rr.w;
        o.x = o.x < 0.0f ? 0.0f : o.x; o.y = o.y < 0.0f ? 0.0f : o.y;
        o.z = o.z < 0.0f ? 0.0f : o.z; o.w = o.w < 0.0f ? 0.0f : o.w;
        *(float4*)&outp[idx] = o;
    }
}

extern "C" void kernel_launch(void* const* d_in, const int* in_sizes, int n_in,
                              void* d_out, int out_size, void* d_ws, size_t ws_size,
                              hipStream_t stream)
{
    const float* x    = (const float*)d_in[0];
    const float* w1   = (const float*)d_in[1];
    const float* cb1  = (const float*)d_in[2];
    const float* g1   = (const float*)d_in[3];
    const float* be1  = (const float*)d_in[4];
    const float* mu1  = (const float*)d_in[5];
    const float* va1  = (const float*)d_in[6];
    const float* w2   = (const float*)d_in[7];
    const float* cb2  = (const float*)d_in[8];
    const float* g2   = (const float*)d_in[9];
    const float* be2  = (const float*)d_in[10];
    const float* mu2  = (const float*)d_in[11];
    const float* va2  = (const float*)d_in[12];
    const float* qw   = (const float*)d_in[13];
    const float* qb_  = (const float*)d_in[14];
    const float* kw   = (const float*)d_in[15];
    const float* kb_  = (const float*)d_in[16];
    const float* vw   = (const float*)d_in[17];
    const float* vb_  = (const float*)d_in[18];
    const float* ow   = (const float*)d_in[19];
    const float* ob_  = (const float*)d_in[20];
    const float* gate = (const float*)d_in[21];

    char* ws = (char*)d_ws;
    bf16*  xk    = (bf16*) (ws + 0);          //  8,388,608  k-blocked x
    bf16*  y1k   = (bf16*) (ws + 8388608);    //  8,388,608  conv1 out k-blocked
    bf16*  c2b   = (bf16*) (ws + 16777216);   //  8,388,608  conv2 out bf16 c-major
    bf16*  attnk = (bf16*) (ws + 25165824);   //  8,388,608  attn out (no aliasing)
    bf16*  qT    = (bf16*) (ws + 33554432);   //  8,388,608  head-blocked
    bf16*  kT    = (bf16*) (ws + 41943040);   //  8,388,608  head-blocked
    bf16*  vbuf  = (bf16*) (ws + 50331648);   //  8,388,608  d-blocked
    bf16*  w1f   = (bf16*) (ws + 58720256);
    bf16*  w2f   = (bf16*) (ws + 59899904);
    bf16*  qwf   = (bf16*) (ws + 61079552);
    bf16*  kwf   = (bf16*) (ws + 61210624);
    bf16*  vwf   = (bf16*) (ws + 61341696);
    bf16*  owf   = (bf16*) (ws + 61472768);

    dim3 blk(256, 1, 1);
    prep_all<<<dim3(1856), blk, 0, stream>>>(x, w1, qw, kw, vw, ow,
                                             xk, w1f, qwf, kwf, vwf, owf);

    phase1_k<<<dim3(2624), blk, 0, stream>>>(w1f, xk, cb1, g1, be1, mu1, va1, y1k,
                                             qwf, kwf, vwf, qb_, kb_, vb_,
                                             qT, kT, vbuf, 0.2550392430300696f,
                                             w2, w2f);
    phase2_k<<<dim3(1536), blk, 0, stream>>>(w2f, y1k, cb2, g2, be2, mu2, va2, c2b,
                                             qT, kT, vbuf, attnk);
    fi_k<<<dim3(1024), blk, 0, stream>>>(owf, attnk, ob_, c2b, x, gate, (float*)d_out);

    (void)in_sizes; (void)n_in; (void)out_size; (void)ws_size;
}